// Round 3
// baseline (4716.256 us; speedup 1.0000x reference)
//
#include <hip/hip_runtime.h>
#include <stdint.h>

typedef unsigned short u16;
typedef unsigned int   u32;
typedef __attribute__((ext_vector_type(8))) short bf16x8;
typedef __attribute__((ext_vector_type(4))) float f32x4;

#define NN    30000
#define EFULL 240000
#define EPAR  30000

__device__ __forceinline__ float b2f(u16 u){ u32 x=((u32)u)<<16; float f; __builtin_memcpy(&f,&x,4); return f; }
__device__ __forceinline__ u16 f2b(float f){ u32 x; __builtin_memcpy(&x,&f,4); x += 0x7fffu + ((x>>16)&1u); return (u16)(x>>16); }

// ---------------- sentinel: workspace too small ----------------
__global__ void k_fail(float* out){ int t=threadIdx.x; if(t<128) out[t]=2.0f; }

// ---------------- CSR build ----------------
__global__ void k_count(const int* __restrict__ dstp, int* __restrict__ cnt, int E){
  int e = blockIdx.x*256 + threadIdx.x;
  if (e < E) atomicAdd(&cnt[dstp[e]], 1);
}

__global__ void k_scan(const int* __restrict__ cnt, int* __restrict__ rp, int* __restrict__ wp){
  __shared__ int sums[1024];
  int t = threadIdx.x;
  const int CH = (NN + 1023)/1024; // 30
  int c0 = t*CH;
  int s = 0;
  for (int i=0;i<CH;i++){ int idx=c0+i; s += (idx<NN)? cnt[idx] : 0; }
  sums[t] = s; __syncthreads();
  for (int off=1; off<1024; off<<=1){
    int v = (t>=off)? sums[t-off] : 0;
    __syncthreads();
    sums[t] += v;
    __syncthreads();
  }
  int run = (t==0)? 0 : sums[t-1];
  for (int i=0;i<CH;i++){
    int idx=c0+i;
    if (idx<NN){ rp[idx]=run; wp[idx]=run; run += cnt[idx]; }
  }
  if (t==1023) rp[NN] = sums[1023];
}

__global__ void k_scan64(const int* __restrict__ cnt, int* __restrict__ rp, int* __restrict__ wp){
  if (threadIdx.x==0){
    int run=0;
    for(int i=0;i<64;i++){ rp[i]=run; wp[i]=run; run+=cnt[i]; }
    rp[64]=run;
  }
}

__global__ void k_fill(const int* __restrict__ dstp, int* __restrict__ wp, int* __restrict__ eix, int E){
  int e = blockIdx.x*256 + threadIdx.x;
  if (e < E){ int p = atomicAdd(&wp[dstp[e]], 1); eix[p] = e; }
}

// ---------------- layer-1 x@W (F=16 -> 512), both L and R, bf16 out ----------------
__global__ __launch_bounds__(256) void k_xw(const float* __restrict__ x,
                                            const float* __restrict__ Wl, const float* __restrict__ Wr,
                                            u16* __restrict__ xl, u16* __restrict__ xr){
  int n = blockIdx.x;
  int c = blockIdx.y*256 + threadIdx.x;
  float xv[16];
  #pragma unroll
  for (int k=0;k<16;k++) xv[k] = x[n*16+k];
  float aL=0.f, aR=0.f;
  #pragma unroll
  for (int k=0;k<16;k++){
    aL += xv[k]*Wl[k*512+c];
    aR += xv[k]*Wr[k*512+c];
  }
  xl[(size_t)n*512+c]=f2b(aL); xr[(size_t)n*512+c]=f2b(aR);
}

// ---------------- edge logits dim=512 (wave per edge) ----------------
__global__ __launch_bounds__(256) void k_edge1(const int* __restrict__ ei, const float* __restrict__ ea,
    const float* __restrict__ We, const float* __restrict__ att,
    const u16* __restrict__ xl, const u16* __restrict__ xr,
    float* __restrict__ ex, int E){
  int lane = threadIdx.x & 63;
  int e = blockIdx.x*4 + (threadIdx.x>>6);
  if (e >= E) return;
  int src = ei[e], dst = ei[E+e];
  float eaw = ea[e];
  int j0 = lane*8;
  bf16x8 lv = *(const bf16x8*)(xl + (size_t)src*512 + j0);
  bf16x8 rv = *(const bf16x8*)(xr + (size_t)dst*512 + j0);
  float logit = 0.f;
  #pragma unroll
  for (int j=0;j<8;j++){
    float v = b2f((u16)lv[j]) + b2f((u16)rv[j]) + eaw*We[j0+j];
    v = v > 0.f ? v : 0.2f*v;
    logit += v * att[j0+j];
  }
  logit += __shfl_xor(logit,1);
  logit += __shfl_xor(logit,2);
  logit += __shfl_xor(logit,4);
  if ((lane&7)==0) ex[(size_t)e*8 + (lane>>3)] = __expf(logit);
}

// ---------------- node aggregation dim=512 (wave per node, CSR), bf16 out ----------------
__global__ __launch_bounds__(256) void k_agg1(const int* __restrict__ ei,
    const int* __restrict__ rp, const int* __restrict__ eix,
    const float* __restrict__ ex, const u16* __restrict__ xl,
    const float* __restrict__ bias, u16* __restrict__ out, int E){
  int lane = threadIdx.x & 63;
  int n = blockIdx.x*4 + (threadIdx.x>>6);
  if (n >= NN) return;
  int r0 = rp[n], r1 = rp[n+1];
  float den = 0.f;
  for (int i = r0 + (lane>>3); i < r1; i += 8)
    den += ex[(size_t)eix[i]*8 + (lane&7)];
  den += __shfl_xor(den,8); den += __shfl_xor(den,16); den += __shfl_xor(den,32);
  float myden = __shfl(den, lane>>3);
  float inv = 1.f/(myden + 1e-16f);
  int j0 = lane*8;
  float acc[8] = {0,0,0,0,0,0,0,0};
  for (int i=r0;i<r1;i++){
    int e = eix[i];
    float a = ex[(size_t)e*8 + (lane>>3)] * inv;
    bf16x8 v = *(const bf16x8*)(xl + (size_t)ei[e]*512 + j0);
    #pragma unroll
    for (int j=0;j<8;j++) acc[j] += a*b2f((u16)v[j]);
  }
  #pragma unroll
  for (int j=0;j<8;j++) out[(size_t)n*512 + j0 + j] = f2b(acc[j] + bias[j0+j]);
}

// ---------------- BN stats (per column over 30000 rows, 512 cols) ----------------
__global__ __launch_bounds__(256) void k_bnstats(const u16* __restrict__ P, float* __restrict__ st){
  int c = blockIdx.x*64 + (threadIdx.x&63);
  int rs0 = blockIdx.y*4 + (threadIdx.x>>6); // 64 row strides total
  float s=0.f, q=0.f;
  for (int r=rs0; r<NN; r+=64){ float v = b2f(P[(size_t)r*512+c]); s+=v; q+=v*v; }
  atomicAdd(&st[c], s);
  atomicAdd(&st[512+c], q);
}

// ---------------- BN apply in-place (bf16), coff selects gamma/beta columns ----------------
__global__ __launch_bounds__(256) void k_bnapply(u16* __restrict__ P, const float* __restrict__ st,
    const float* __restrict__ g, const float* __restrict__ b, int coff){
  int idx = blockIdx.x*256 + threadIdx.x;
  if (idx >= NN*512) return;
  int c = idx & 511;
  const float invN = 1.f/30000.f;
  float mu = st[c]*invN;
  float var = st[512+c]*invN - mu*mu;
  float r = rsqrtf(var + 1e-5f);
  float v = b2f(P[idx]);
  P[idx] = f2b((v-mu)*r*g[coff+c] + b[coff+c]);
}

// ---------------- MFMA GEMM: CAT[M,2048] = [A0|A1][M,1024] @ [Wl3 | Wr3], bf16 out ----------------
#define LDP 40
__global__ __launch_bounds__(256) void k_gemm(const u16* __restrict__ A0, const u16* __restrict__ A1,
    const float* __restrict__ B0, const float* __restrict__ B1,
    u16* __restrict__ C, int M){
  __shared__ u16 As[128*LDP];
  __shared__ u16 Bs[128*LDP];
  int m0 = blockIdx.x*128;
  int n0 = blockIdx.y*128;
  const float* B = (n0 < 1024) ? B0 : B1;
  int nc0 = n0 & 1023;
  int t = threadIdx.x;
  int wave = t>>6, lane = t&63;
  int wm = (wave>>1)*64, wn = (wave&1)*64;
  int rr = lane&15, kq = (lane>>4)*8;
  f32x4 acc[4][4];
  #pragma unroll
  for (int m=0;m<4;m++)
    #pragma unroll
    for (int n=0;n<4;n++){ acc[m][n][0]=0.f; acc[m][n][1]=0.f; acc[m][n][2]=0.f; acc[m][n][3]=0.f; }
  for (int k0=0; k0<1024; k0+=32){
    const u16* Ap = (k0 < 512) ? A0 : A1;
    int kc = k0 & 511;
    // stage A: 128 rows x 32 k (bf16 already)
    #pragma unroll
    for (int i=0;i<2;i++){
      int ch = i*256 + t;
      int row = ch>>2, ko = (ch&3)*8;
      int gr = m0 + row;
      uint4 v = make_uint4(0u,0u,0u,0u);
      if (gr < M) v = *(const uint4*)(Ap + (size_t)gr*512 + kc + ko);
      *(uint4*)(&As[row*LDP + ko]) = v;
    }
    // stage B transposed: Bs[n][k], f32 -> bf16
    #pragma unroll
    for (int i=0;i<2;i++){
      int ch = i*256 + t;
      int kk = ch>>4, nn = (ch&15)*8;
      const float* src = B + (size_t)(k0+kk)*1024 + nc0 + nn;
      float4 v0 = *(const float4*)(src);
      float4 v1 = *(const float4*)(src+4);
      Bs[(nn+0)*LDP + kk] = f2b(v0.x);
      Bs[(nn+1)*LDP + kk] = f2b(v0.y);
      Bs[(nn+2)*LDP + kk] = f2b(v0.z);
      Bs[(nn+3)*LDP + kk] = f2b(v0.w);
      Bs[(nn+4)*LDP + kk] = f2b(v1.x);
      Bs[(nn+5)*LDP + kk] = f2b(v1.y);
      Bs[(nn+6)*LDP + kk] = f2b(v1.z);
      Bs[(nn+7)*LDP + kk] = f2b(v1.w);
    }
    __syncthreads();
    bf16x8 af[4], bb[4];
    #pragma unroll
    for (int m=0;m<4;m++) af[m] = *(const bf16x8*)(&As[(wm + m*16 + rr)*LDP + kq]);
    #pragma unroll
    for (int n=0;n<4;n++) bb[n] = *(const bf16x8*)(&Bs[(wn + n*16 + rr)*LDP + kq]);
    #pragma unroll
    for (int m=0;m<4;m++)
      #pragma unroll
      for (int n=0;n<4;n++)
        acc[m][n] = __builtin_amdgcn_mfma_f32_16x16x32_bf16(af[m], bb[n], acc[m][n], 0, 0, 0);
    __syncthreads();
  }
  int rq = (lane>>4)*4;
  #pragma unroll
  for (int m=0;m<4;m++)
    #pragma unroll
    for (int n=0;n<4;n++)
      #pragma unroll
      for (int j=0;j<4;j++){
        int row = m0 + wm + m*16 + rq + j;
        int col = n0 + wn + n*16 + rr;
        if (row < M) C[(size_t)row*2048 + col] = f2b(acc[m][n][j]);
      }
}

// ---------------- edge logits dim=1024 (layer 2, CAT bf16) ----------------
__global__ __launch_bounds__(256) void k_edge2(const int* __restrict__ ei, const float* __restrict__ ea,
    const float* __restrict__ We, const float* __restrict__ att,
    const u16* __restrict__ CAT, float* __restrict__ ex, int E){
  int lane = threadIdx.x & 63;
  int e = blockIdx.x*4 + (threadIdx.x>>6);
  if (e >= E) return;
  int src = ei[e], dst = ei[E+e];
  float eaw = ea[e];
  int j0 = lane*16;
  bf16x8 l0 = *(const bf16x8*)(CAT + (size_t)src*2048 + j0);
  bf16x8 l1 = *(const bf16x8*)(CAT + (size_t)src*2048 + j0 + 8);
  bf16x8 r0 = *(const bf16x8*)(CAT + (size_t)dst*2048 + 1024 + j0);
  bf16x8 r1 = *(const bf16x8*)(CAT + (size_t)dst*2048 + 1024 + j0 + 8);
  float logit = 0.f;
  #pragma unroll
  for (int j=0;j<16;j++){
    float lvj = b2f((u16)((j<8)? l0[j] : l1[j-8]));
    float rvj = b2f((u16)((j<8)? r0[j] : r1[j-8]));
    float v = lvj + rvj + eaw*We[j0+j];
    v = v > 0.f ? v : 0.2f*v;
    logit += v * att[j0+j];
  }
  logit += __shfl_xor(logit,1);
  logit += __shfl_xor(logit,2);
  logit += __shfl_xor(logit,4);
  if ((lane&7)==0) ex[(size_t)e*8 + (lane>>3)] = __expf(logit);
}

// ---------------- fused layer-2 aggregation + route pooling ----------------
__global__ __launch_bounds__(256) void k_agg2pool(const int* __restrict__ ei,
    const int* __restrict__ rp, const int* __restrict__ eix,
    const int* __restrict__ rrp, const int* __restrict__ nix,
    const float* __restrict__ ex, const u16* __restrict__ CAT,
    const float* __restrict__ b3, float* __restrict__ rs){
  int r = blockIdx.x;                      // 0..63
  int c = blockIdx.y*256 + threadIdx.x;    // 0..1023
  int h = c >> 7;
  int i0 = rrp[r], i1 = rrp[r+1];
  float acc = 0.f;
  for (int i=i0;i<i1;i++){
    int n = nix[i];
    int e0 = rp[n], e1 = rp[n+1];
    float den = 0.f;
    for (int t=e0;t<e1;t++) den += ex[(size_t)eix[t]*8 + h];
    float inv = 1.f/(den + 1e-16f);
    for (int t=e0;t<e1;t++){
      int e = eix[t];
      acc += ex[(size_t)e*8 + h] * inv * b2f(CAT[(size_t)ei[e]*2048 + c]);
    }
  }
  rs[r*1024 + c] = acc + (float)(i1-i0)*b3[c];
}

// ---------------- cumsum over routes -> ptop halves ----------------
__global__ void k_cumsum(const float* __restrict__ rs, float* __restrict__ ptop, int colbase){
  int c = blockIdx.x*256 + threadIdx.x; // 1024 cols
  float tot = 0.f;
  for (int r=0;r<64;r++) tot += rs[r*1024+c];
  float cs = 0.f;
  for (int r=0;r<64;r++){
    cs += rs[r*1024+c];
    ptop[r*4096 + colbase + c] = cs;
    ptop[r*4096 + colbase + 1024 + c] = tot - cs;
  }
}

// ---------------- BN over 64 routes (per column) ----------------
__global__ void k_pnbn(const float* __restrict__ ptop, const float* __restrict__ g, const float* __restrict__ b,
                       float* __restrict__ h){
  int c = blockIdx.x*256 + threadIdx.x; // 4096 cols
  float s=0.f, q=0.f;
  for (int r=0;r<64;r++){ float v = ptop[r*4096+c]; s+=v; q+=v*v; }
  float mu = s*(1.f/64.f), var = q*(1.f/64.f)-mu*mu;
  float rr = rsqrtf(var + 1e-5f);
  float gg = g[c], bb = b[c];
  for (int r=0;r<64;r++) h[r*4096+c] = (ptop[r*4096+c]-mu)*rr*gg + bb;
}

// ---------------- generic MLP layer: Out[64,Co] = act(In[64,Ci] @ W + bias) ----------------
__global__ __launch_bounds__(256) void k_mlp(const float* __restrict__ In, const float* __restrict__ W,
    const float* __restrict__ bias, float* __restrict__ Out, int Ci, int Co, int act){
  __shared__ float tin[64*64]; // 16 KiB
  int t = threadIdx.x;
  int c = blockIdx.x*16 + (t&15);
  int rg = t>>4; // 0..15, each owns 4 rows
  float a0=0.f,a1=0.f,a2=0.f,a3=0.f;
  for (int k0=0;k0<Ci;k0+=64){
    __syncthreads();
    for (int i=t;i<4096;i+=256){
      int r=i>>6, k=i&63;
      tin[i] = (k0+k < Ci) ? In[(size_t)r*Ci + k0 + k] : 0.f;
    }
    __syncthreads();
    if (c < Co){
      int kmax = min(64, Ci-k0);
      for (int k=0;k<kmax;k++){
        float w = W[(size_t)(k0+k)*Co + c];
        a0 += tin[(rg*4+0)*64+k]*w;
        a1 += tin[(rg*4+1)*64+k]*w;
        a2 += tin[(rg*4+2)*64+k]*w;
        a3 += tin[(rg*4+3)*64+k]*w;
      }
    }
  }
  if (c < Co){
    float bb = bias[c];
    float v[4] = {a0+bb, a1+bb, a2+bb, a3+bb};
    #pragma unroll
    for (int j=0;j<4;j++){
      float o = v[j];
      if (act) o = o > 0.f ? o : 0.01f*o;
      Out[(size_t)(rg*4+j)*Co + c] = o;
    }
  }
}

// ---------------- sigmoid + output (f32) ----------------
__global__ void k_sigout(const float* __restrict__ h8, float* __restrict__ out){
  int r = threadIdx.x;
  if (r < 64){
    float p = 1.f/(1.f + __expf(-h8[r]));
    out[r] = p;
    out[64+r] = 0.f;   // ptop_batch zeros (int32 0 bit pattern == f32 0.0)
  }
}

extern "C" void kernel_launch(void* const* d_in, const int* in_sizes, int n_in,
                              void* d_out, int out_size, void* d_ws, size_t ws_size,
                              hipStream_t stream)
{
  const float* x_p1   = (const float*)d_in[0];
  const float* x_p2   = (const float*)d_in[1];
  const float* x_full = (const float*)d_in[2];
  const float* ea_p1  = (const float*)d_in[3];
  const float* ea_p2  = (const float*)d_in[4];
  const float* ea_full= (const float*)d_in[5];
  const int* ei_p1  = (const int*)d_in[6];
  const int* ei_p2  = (const int*)d_in[7];
  const int* ei_full= (const int*)d_in[8];
  const int* route_p1 = (const int*)d_in[9];
  const int* route_p2 = (const int*)d_in[10];
  const float *Wl1=(const float*)d_in[11], *Wr1=(const float*)d_in[12], *We1=(const float*)d_in[13], *att1=(const float*)d_in[14], *b1=(const float*)d_in[15];
  const float *Wl2=(const float*)d_in[16], *Wr2=(const float*)d_in[17], *We2=(const float*)d_in[18], *att2=(const float*)d_in[19], *b2=(const float*)d_in[20];
  const float *Wl3=(const float*)d_in[21], *Wr3=(const float*)d_in[22], *We3=(const float*)d_in[23], *att3=(const float*)d_in[24], *b3=(const float*)d_in[25];
  const float *bng=(const float*)d_in[26], *bnb=(const float*)d_in[27], *png=(const float*)d_in[28], *pnb=(const float*)d_in[29];
  const float *W[8], *Cb[8];
  for (int i=0;i<8;i++){ W[i]=(const float*)d_in[30+2*i]; Cb[i]=(const float*)d_in[31+2*i]; }

  char* w = (char*)d_ws;
  size_t off = 0;
  auto alloc = [&](size_t bytes)->char*{ char* p = w + off; off += (bytes + 255) & ~(size_t)255; return p; };
  u16* P1bf = (u16*)alloc((size_t)NN*512*2);
  u16* P2bf = (u16*)alloc((size_t)NN*512*2);
  u16* FGbf = (u16*)alloc((size_t)NN*512*2);
  char* BIG = alloc((size_t)NN*2048*2);           // phase1: XL|XR|EXf  phase3: CAT
  u16*   XLbf = (u16*)BIG;
  u16*   XRbf = (u16*)(BIG + (size_t)NN*512*2);
  float* EXf  = (float*)(BIG + (size_t)NN*1024*2);
  u16*   CATbf= (u16*)BIG;
  float* EX2 = (float*)alloc((size_t)EPAR*8*4);
  float* st1 = (float*)alloc(1024*4);
  float* st2 = (float*)alloc(1024*4);
  float* stF = (float*)alloc(1024*4);
  float* rs1 = (float*)alloc(64*1024*4);
  float* rs2 = (float*)alloc(64*1024*4);
  float* PTOP= (float*)alloc(64*4096*4);
  float* H0  = (float*)alloc(64*4096*4);
  float* H1  = (float*)alloc(64*4096*4);
  int* cnt = (int*)alloc(NN*4);
  int* wp  = (int*)alloc(NN*4);
  int* rpF = (int*)alloc((NN+1)*4);
  int* rp1 = (int*)alloc((NN+1)*4);
  int* rp2 = (int*)alloc((NN+1)*4);
  int* eixF= (int*)alloc((size_t)EFULL*4);
  int* eix1= (int*)alloc((size_t)EPAR*4);
  int* eix2= (int*)alloc((size_t)EPAR*4);
  int* rr1 = (int*)alloc(65*4);
  int* rr2 = (int*)alloc(65*4);
  int* nix1= (int*)alloc(NN*4);
  int* nix2= (int*)alloc(NN*4);
  if (ws_size < off){ k_fail<<<1,128,0,stream>>>((float*)d_out); return; }

  // ---- CSR builds (edges by dst) ----
  auto build_csr = [&](const int* dstp, int E, int* rp, int* eix){
    hipMemsetAsync(cnt, 0, NN*4, stream);
    k_count<<<(E+255)/256, 256, 0, stream>>>(dstp, cnt, E);
    k_scan <<<1, 1024, 0, stream>>>(cnt, rp, wp);
    k_fill <<<(E+255)/256, 256, 0, stream>>>(dstp, wp, eix, E);
  };
  build_csr(ei_full+EFULL, EFULL, rpF, eixF);
  build_csr(ei_p1+EPAR,   EPAR,  rp1, eix1);
  build_csr(ei_p2+EPAR,   EPAR,  rp2, eix2);

  // ---- route CSR (nodes by route) ----
  auto build_route = [&](const int* route, int* rrp, int* nix){
    hipMemsetAsync(cnt, 0, 64*4, stream);
    k_count <<<(NN+255)/256, 256, 0, stream>>>(route, cnt, NN);
    k_scan64<<<1, 64, 0, stream>>>(cnt, rrp, wp);
    k_fill  <<<(NN+255)/256, 256, 0, stream>>>(route, wp, nix, NN);
  };
  build_route(route_p1, rr1, nix1);
  build_route(route_p2, rr2, nix2);

  // ---- layer-1 GAT (three graphs, sequential, shared XL/XR/EX temps) ----
  auto gat1 = [&](const float* x, const int* ei, const float* ea, const int* rp, const int* eix,
                  const float* Wl, const float* Wr, const float* We, const float* att, const float* bias,
                  u16* out, int E){
    k_xw   <<<dim3(NN,2), 256, 0, stream>>>(x, Wl, Wr, XLbf, XRbf);
    k_edge1<<<(E+3)/4,  256, 0, stream>>>(ei, ea, We, att, XLbf, XRbf, EXf, E);
    k_agg1 <<<(NN+3)/4, 256, 0, stream>>>(ei, rp, eix, EXf, XLbf, bias, out, E);
  };
  gat1(x_full, ei_full, ea_full, rpF, eixF, Wl2, Wr2, We2, att2, b2, FGbf, EFULL);
  gat1(x_p1,   ei_p1,   ea_p1,   rp1, eix1, Wl1, Wr1, We1, att1, b1, P1bf, EPAR);
  gat1(x_p2,   ei_p2,   ea_p2,   rp2, eix2, Wl1, Wr1, We1, att1, b1, P2bf, EPAR);

  // ---- BatchNorm (batch stats) applied in place; FG half normalized once ----
  hipMemsetAsync(st1, 0, 1024*4, stream);
  hipMemsetAsync(st2, 0, 1024*4, stream);
  hipMemsetAsync(stF, 0, 1024*4, stream);
  k_bnstats<<<dim3(8,16), 256, 0, stream>>>(P1bf, st1);
  k_bnstats<<<dim3(8,16), 256, 0, stream>>>(P2bf, st2);
  k_bnstats<<<dim3(8,16), 256, 0, stream>>>(FGbf, stF);
  int nbn = (NN*512+255)/256;
  k_bnapply<<<nbn, 256, 0, stream>>>(P1bf, st1, bng, bnb, 0);
  k_bnapply<<<nbn, 256, 0, stream>>>(P2bf, st2, bng, bnb, 0);
  k_bnapply<<<nbn, 256, 0, stream>>>(FGbf, stF, bng, bnb, 512);

  // ---- layer-2 GAT + fused route pooling, per parent ----
  auto layer2 = [&](const u16* Pbf, const int* ei, const float* ea, const int* rp, const int* eix,
                    const int* rrp, const int* nix, float* rs){
    k_gemm <<<dim3((NN+127)/128, 16), 256, 0, stream>>>(Pbf, FGbf, Wl3, Wr3, CATbf, NN);
    k_edge2<<<(EPAR+3)/4, 256, 0, stream>>>(ei, ea, We3, att3, CATbf, EX2, EPAR);
    k_agg2pool<<<dim3(64,4), 256, 0, stream>>>(ei, rp, eix, rrp, nix, EX2, CATbf, b3, rs);
  };
  layer2(P1bf, ei_p1, ea_p1, rp1, eix1, rr1, nix1, rs1);
  layer2(P2bf, ei_p2, ea_p2, rp2, eix2, rr2, nix2, rs2);

  // ---- cumsum/route features + pn BN ----
  k_cumsum<<<4, 256, 0, stream>>>(rs1, PTOP, 0);
  k_cumsum<<<4, 256, 0, stream>>>(rs2, PTOP, 2048);
  k_pnbn  <<<16, 256, 0, stream>>>(PTOP, png, pnb, H0);

  // ---- MLP ----
  int dims[9] = {4096, 2048, 1024, 512, 256, 128, 64, 32, 1};
  float* bufs[2] = {H0, H1};
  for (int i=0;i<8;i++){
    k_mlp<<<(dims[i+1]+15)/16, 256, 0, stream>>>(bufs[i&1], W[i], Cb[i], bufs[(i+1)&1],
                                                 dims[i], dims[i+1], (i<7)?1:0);
  }
  k_sigout<<<1, 64, 0, stream>>>(bufs[0], (float*)d_out);
}

// Round 4
// 3995.415 us; speedup vs baseline: 1.1804x; 1.1804x over previous
//
#include <hip/hip_runtime.h>
#include <stdint.h>

typedef unsigned short u16;
typedef unsigned int   u32;
typedef __attribute__((ext_vector_type(8))) short bf16x8;
typedef __attribute__((ext_vector_type(4))) float f32x4;

#define NN    30000
#define EFULL 240000
#define EPAR  30000

__device__ __forceinline__ float b2f(u16 u){ u32 x=((u32)u)<<16; float f; __builtin_memcpy(&f,&x,4); return f; }
__device__ __forceinline__ u16 f2b(float f){ u32 x; __builtin_memcpy(&x,&f,4); x += 0x7fffu + ((x>>16)&1u); return (u16)(x>>16); }

// ---------------- sentinel: workspace too small ----------------
__global__ void k_fail(float* out){ int t=threadIdx.x; if(t<128) out[t]=2.0f; }

// ---------------- CSR build ----------------
__global__ void k_count(const int* __restrict__ dstp, int* __restrict__ cnt, int E){
  int e = blockIdx.x*256 + threadIdx.x;
  if (e < E) atomicAdd(&cnt[dstp[e]], 1);
}

__global__ void k_scan(const int* __restrict__ cnt, int* __restrict__ rp, int* __restrict__ wp){
  __shared__ int sums[1024];
  int t = threadIdx.x;
  const int CH = (NN + 1023)/1024; // 30
  int c0 = t*CH;
  int s = 0;
  for (int i=0;i<CH;i++){ int idx=c0+i; s += (idx<NN)? cnt[idx] : 0; }
  sums[t] = s; __syncthreads();
  for (int off=1; off<1024; off<<=1){
    int v = (t>=off)? sums[t-off] : 0;
    __syncthreads();
    sums[t] += v;
    __syncthreads();
  }
  int run = (t==0)? 0 : sums[t-1];
  for (int i=0;i<CH;i++){
    int idx=c0+i;
    if (idx<NN){ rp[idx]=run; wp[idx]=run; run += cnt[idx]; }
  }
  if (t==1023) rp[NN] = sums[1023];
}

__global__ void k_scan64(const int* __restrict__ cnt, int* __restrict__ rp, int* __restrict__ wp){
  if (threadIdx.x==0){
    int run=0;
    for(int i=0;i<64;i++){ rp[i]=run; wp[i]=run; run+=cnt[i]; }
    rp[64]=run;
  }
}

__global__ void k_fill(const int* __restrict__ dstp, int* __restrict__ wp, int* __restrict__ eix, int E){
  int e = blockIdx.x*256 + threadIdx.x;
  if (e < E){ int p = atomicAdd(&wp[dstp[e]], 1); eix[p] = e; }
}

// ---------------- layer-1 x@W (F=16 -> 512), both L and R, bf16 out ----------------
__global__ __launch_bounds__(256) void k_xw(const float* __restrict__ x,
                                            const float* __restrict__ Wl, const float* __restrict__ Wr,
                                            u16* __restrict__ xl, u16* __restrict__ xr){
  int n = blockIdx.x;
  int c = blockIdx.y*256 + threadIdx.x;
  float xv[16];
  #pragma unroll
  for (int k=0;k<16;k++) xv[k] = x[n*16+k];
  float aL=0.f, aR=0.f;
  #pragma unroll
  for (int k=0;k<16;k++){
    aL += xv[k]*Wl[k*512+c];
    aR += xv[k]*Wr[k*512+c];
  }
  xl[(size_t)n*512+c]=f2b(aL); xr[(size_t)n*512+c]=f2b(aR);
}

// ---------------- edge logits dim=512 (wave per edge) ----------------
__global__ __launch_bounds__(256) void k_edge1(const int* __restrict__ ei, const float* __restrict__ ea,
    const float* __restrict__ We, const float* __restrict__ att,
    const u16* __restrict__ xl, const u16* __restrict__ xr,
    float* __restrict__ ex, int E){
  int lane = threadIdx.x & 63;
  int e = blockIdx.x*4 + (threadIdx.x>>6);
  if (e >= E) return;
  int src = ei[e], dst = ei[E+e];
  float eaw = ea[e];
  int j0 = lane*8;
  bf16x8 lv = *(const bf16x8*)(xl + (size_t)src*512 + j0);
  bf16x8 rv = *(const bf16x8*)(xr + (size_t)dst*512 + j0);
  float logit = 0.f;
  #pragma unroll
  for (int j=0;j<8;j++){
    float v = b2f((u16)lv[j]) + b2f((u16)rv[j]) + eaw*We[j0+j];
    v = v > 0.f ? v : 0.2f*v;
    logit += v * att[j0+j];
  }
  logit += __shfl_xor(logit,1);
  logit += __shfl_xor(logit,2);
  logit += __shfl_xor(logit,4);
  if ((lane&7)==0) ex[(size_t)e*8 + (lane>>3)] = __expf(logit);
}

// ---------------- node aggregation dim=512 (wave per node, CSR), bf16 out ----------------
__global__ __launch_bounds__(256) void k_agg1(const int* __restrict__ ei,
    const int* __restrict__ rp, const int* __restrict__ eix,
    const float* __restrict__ ex, const u16* __restrict__ xl,
    const float* __restrict__ bias, u16* __restrict__ out, int E){
  int lane = threadIdx.x & 63;
  int n = blockIdx.x*4 + (threadIdx.x>>6);
  if (n >= NN) return;
  int r0 = rp[n], r1 = rp[n+1];
  float den = 0.f;
  for (int i = r0 + (lane>>3); i < r1; i += 8)
    den += ex[(size_t)eix[i]*8 + (lane&7)];
  den += __shfl_xor(den,8); den += __shfl_xor(den,16); den += __shfl_xor(den,32);
  float myden = __shfl(den, lane>>3);
  float inv = 1.f/(myden + 1e-16f);
  int j0 = lane*8;
  float acc[8] = {0,0,0,0,0,0,0,0};
  for (int i=r0;i<r1;i++){
    int e = eix[i];
    float a = ex[(size_t)e*8 + (lane>>3)] * inv;
    bf16x8 v = *(const bf16x8*)(xl + (size_t)ei[e]*512 + j0);
    #pragma unroll
    for (int j=0;j<8;j++) acc[j] += a*b2f((u16)v[j]);
  }
  #pragma unroll
  for (int j=0;j<8;j++) out[(size_t)n*512 + j0 + j] = f2b(acc[j] + bias[j0+j]);
}

// ---------------- BN stats (per column over 30000 rows, 512 cols) ----------------
__global__ __launch_bounds__(256) void k_bnstats(const u16* __restrict__ P, float* __restrict__ st){
  int c = blockIdx.x*64 + (threadIdx.x&63);
  int rs0 = blockIdx.y*4 + (threadIdx.x>>6); // 64 row strides total
  float s=0.f, q=0.f;
  for (int r=rs0; r<NN; r+=64){ float v = b2f(P[(size_t)r*512+c]); s+=v; q+=v*v; }
  atomicAdd(&st[c], s);
  atomicAdd(&st[512+c], q);
}

// ---------------- BN apply in-place (bf16), coff selects gamma/beta columns ----------------
__global__ __launch_bounds__(256) void k_bnapply(u16* __restrict__ P, const float* __restrict__ st,
    const float* __restrict__ g, const float* __restrict__ b, int coff){
  int idx = blockIdx.x*256 + threadIdx.x;
  if (idx >= NN*512) return;
  int c = idx & 511;
  const float invN = 1.f/30000.f;
  float mu = st[c]*invN;
  float var = st[512+c]*invN - mu*mu;
  float r = rsqrtf(var + 1e-5f);
  float v = b2f(P[idx]);
  P[idx] = f2b((v-mu)*r*g[coff+c] + b[coff+c]);
}

// ---------------- MFMA GEMM: CAT[M,2048] = [A0|A1][M,1024] @ [Wl3 | Wr3], bf16 out ----------------
#define LDP 40
__global__ __launch_bounds__(256) void k_gemm(const u16* __restrict__ A0, const u16* __restrict__ A1,
    const float* __restrict__ B0, const float* __restrict__ B1,
    u16* __restrict__ C, int M){
  __shared__ u16 As[128*LDP];
  __shared__ u16 Bs[128*LDP];
  int m0 = blockIdx.x*128;
  int n0 = blockIdx.y*128;
  const float* B = (n0 < 1024) ? B0 : B1;
  int nc0 = n0 & 1023;
  int t = threadIdx.x;
  int wave = t>>6, lane = t&63;
  int wm = (wave>>1)*64, wn = (wave&1)*64;
  int rr = lane&15, kq = (lane>>4)*8;
  f32x4 acc[4][4];
  #pragma unroll
  for (int m=0;m<4;m++)
    #pragma unroll
    for (int n=0;n<4;n++){ acc[m][n][0]=0.f; acc[m][n][1]=0.f; acc[m][n][2]=0.f; acc[m][n][3]=0.f; }
  for (int k0=0; k0<1024; k0+=32){
    const u16* Ap = (k0 < 512) ? A0 : A1;
    int kc = k0 & 511;
    #pragma unroll
    for (int i=0;i<2;i++){
      int ch = i*256 + t;
      int row = ch>>2, ko = (ch&3)*8;
      int gr = m0 + row;
      uint4 v = make_uint4(0u,0u,0u,0u);
      if (gr < M) v = *(const uint4*)(Ap + (size_t)gr*512 + kc + ko);
      *(uint4*)(&As[row*LDP + ko]) = v;
    }
    #pragma unroll
    for (int i=0;i<2;i++){
      int ch = i*256 + t;
      int kk = ch>>4, nn = (ch&15)*8;
      const float* src = B + (size_t)(k0+kk)*1024 + nc0 + nn;
      float4 v0 = *(const float4*)(src);
      float4 v1 = *(const float4*)(src+4);
      Bs[(nn+0)*LDP + kk] = f2b(v0.x);
      Bs[(nn+1)*LDP + kk] = f2b(v0.y);
      Bs[(nn+2)*LDP + kk] = f2b(v0.z);
      Bs[(nn+3)*LDP + kk] = f2b(v0.w);
      Bs[(nn+4)*LDP + kk] = f2b(v1.x);
      Bs[(nn+5)*LDP + kk] = f2b(v1.y);
      Bs[(nn+6)*LDP + kk] = f2b(v1.z);
      Bs[(nn+7)*LDP + kk] = f2b(v1.w);
    }
    __syncthreads();
    bf16x8 af[4], bb[4];
    #pragma unroll
    for (int m=0;m<4;m++) af[m] = *(const bf16x8*)(&As[(wm + m*16 + rr)*LDP + kq]);
    #pragma unroll
    for (int n=0;n<4;n++) bb[n] = *(const bf16x8*)(&Bs[(wn + n*16 + rr)*LDP + kq]);
    #pragma unroll
    for (int m=0;m<4;m++)
      #pragma unroll
      for (int n=0;n<4;n++)
        acc[m][n] = __builtin_amdgcn_mfma_f32_16x16x32_bf16(af[m], bb[n], acc[m][n], 0, 0, 0);
    __syncthreads();
  }
  int rq = (lane>>4)*4;
  #pragma unroll
  for (int m=0;m<4;m++)
    #pragma unroll
    for (int n=0;n<4;n++)
      #pragma unroll
      for (int j=0;j<4;j++){
        int row = m0 + wm + m*16 + rq + j;
        int col = n0 + wn + n*16 + rr;
        if (row < M) C[(size_t)row*2048 + col] = f2b(acc[m][n][j]);
      }
}

// ---------------- edge logits dim=1024 (layer 2, CAT bf16) ----------------
__global__ __launch_bounds__(256) void k_edge2(const int* __restrict__ ei, const float* __restrict__ ea,
    const float* __restrict__ We, const float* __restrict__ att,
    const u16* __restrict__ CAT, float* __restrict__ ex, int E){
  int lane = threadIdx.x & 63;
  int e = blockIdx.x*4 + (threadIdx.x>>6);
  if (e >= E) return;
  int src = ei[e], dst = ei[E+e];
  float eaw = ea[e];
  int j0 = lane*16;
  bf16x8 l0 = *(const bf16x8*)(CAT + (size_t)src*2048 + j0);
  bf16x8 l1 = *(const bf16x8*)(CAT + (size_t)src*2048 + j0 + 8);
  bf16x8 r0 = *(const bf16x8*)(CAT + (size_t)dst*2048 + 1024 + j0);
  bf16x8 r1 = *(const bf16x8*)(CAT + (size_t)dst*2048 + 1024 + j0 + 8);
  float logit = 0.f;
  #pragma unroll
  for (int j=0;j<16;j++){
    float lvj = b2f((u16)((j<8)? l0[j] : l1[j-8]));
    float rvj = b2f((u16)((j<8)? r0[j] : r1[j-8]));
    float v = lvj + rvj + eaw*We[j0+j];
    v = v > 0.f ? v : 0.2f*v;
    logit += v * att[j0+j];
  }
  logit += __shfl_xor(logit,1);
  logit += __shfl_xor(logit,2);
  logit += __shfl_xor(logit,4);
  if ((lane&7)==0) ex[(size_t)e*8 + (lane>>3)] = __expf(logit);
}

// ---------------- fused layer-2 aggregation + route pooling ----------------
__global__ __launch_bounds__(256) void k_agg2pool(const int* __restrict__ ei,
    const int* __restrict__ rp, const int* __restrict__ eix,
    const int* __restrict__ rrp, const int* __restrict__ nix,
    const float* __restrict__ ex, const u16* __restrict__ CAT,
    const float* __restrict__ b3, float* __restrict__ rs){
  int r = blockIdx.x;                      // 0..63
  int c = blockIdx.y*256 + threadIdx.x;    // 0..1023
  int h = c >> 7;
  int i0 = rrp[r], i1 = rrp[r+1];
  float acc = 0.f;
  for (int i=i0;i<i1;i++){
    int n = nix[i];
    int e0 = rp[n], e1 = rp[n+1];
    float den = 0.f;
    for (int t=e0;t<e1;t++) den += ex[(size_t)eix[t]*8 + h];
    float inv = 1.f/(den + 1e-16f);
    for (int t=e0;t<e1;t++){
      int e = eix[t];
      acc += ex[(size_t)e*8 + h] * inv * b2f(CAT[(size_t)ei[e]*2048 + c]);
    }
  }
  rs[r*1024 + c] = acc + (float)(i1-i0)*b3[c];
}

// ---------------- cumsum over routes -> ptop halves ----------------
__global__ void k_cumsum(const float* __restrict__ rs, float* __restrict__ ptop, int colbase){
  int c = blockIdx.x*256 + threadIdx.x; // 1024 cols
  float tot = 0.f;
  for (int r=0;r<64;r++) tot += rs[r*1024+c];
  float cs = 0.f;
  for (int r=0;r<64;r++){
    cs += rs[r*1024+c];
    ptop[r*4096 + colbase + c] = cs;
    ptop[r*4096 + colbase + 1024 + c] = tot - cs;
  }
}

// ---------------- BN over 64 routes (per column) ----------------
__global__ void k_pnbn(const float* __restrict__ ptop, const float* __restrict__ g, const float* __restrict__ b,
                       float* __restrict__ h){
  int c = blockIdx.x*256 + threadIdx.x; // 4096 cols
  float s=0.f, q=0.f;
  for (int r=0;r<64;r++){ float v = ptop[r*4096+c]; s+=v; q+=v*v; }
  float mu = s*(1.f/64.f), var = q*(1.f/64.f)-mu*mu;
  float rr = rsqrtf(var + 1e-5f);
  float gg = g[c], bb = b[c];
  for (int r=0;r<64;r++) h[r*4096+c] = (ptop[r*4096+c]-mu)*rr*gg + bb;
}

// ---------------- MLP split-K partials: PART[sk][64][Co] ----------------
// block: 256 thr = 64 cols x 4 row-groups(16 rows). grid: (ceil(Co/64), SK)
#define KC 512
__global__ __launch_bounds__(256) void k_mlp_part(const float* __restrict__ In,
    const float* __restrict__ W, float* __restrict__ PART, int Ci, int Co){
  __shared__ float tin[64*64]; // 16 KiB: rows x ksub
  int c  = blockIdx.x*64 + (threadIdx.x&63);
  int rg = threadIdx.x>>6;     // 0..3
  int k0 = blockIdx.y*KC, k1 = min(Ci, k0+KC);
  float acc[16];
  #pragma unroll
  for (int j=0;j<16;j++) acc[j]=0.f;
  for (int ks=k0; ks<k1; ks+=64){
    int kw = min(64, k1-ks);
    __syncthreads();
    for (int i=threadIdx.x;i<64*64;i+=256){
      int r=i>>6, k=i&63;
      tin[i] = (k<kw)? In[(size_t)r*Ci + ks + k] : 0.f;
    }
    __syncthreads();
    if (c < Co){
      for (int k=0;k<kw;k+=4){
        float4 w4;
        w4.x = W[(size_t)(ks+k  )*Co + c];
        w4.y = W[(size_t)(ks+k+1)*Co + c];
        w4.z = W[(size_t)(ks+k+2)*Co + c];
        w4.w = W[(size_t)(ks+k+3)*Co + c];
        #pragma unroll
        for (int j=0;j<16;j++){
          float4 t4 = *(const float4*)(&tin[(rg*16+j)*64 + k]); // broadcast read
          acc[j] += t4.x*w4.x + t4.y*w4.y + t4.z*w4.z + t4.w*w4.w;
        }
      }
    }
  }
  if (c < Co){
    float* P = PART + (size_t)blockIdx.y*64*Co;
    #pragma unroll
    for (int j=0;j<16;j++)
      P[(size_t)(rg*16+j)*Co + c] = acc[j];
  }
}

// ---------------- MLP reduce: Out = act(sum_sk PART + bias) ----------------
__global__ void k_mlp_red(const float* __restrict__ PART, const float* __restrict__ bias,
                          float* __restrict__ Out, int Co, int SK, int act){
  int idx = blockIdx.x*256 + threadIdx.x;
  if (idx >= 64*Co) return;
  int c = idx % Co;
  float s = bias[c];
  for (int sk=0; sk<SK; sk++) s += PART[(size_t)sk*64*Co + idx];
  if (act) s = s>0.f ? s : 0.01f*s;
  Out[idx] = s;
}

// ---------------- sigmoid + output (f32) ----------------
__global__ void k_sigout(const float* __restrict__ h8, float* __restrict__ out){
  int r = threadIdx.x;
  if (r < 64){
    float p = 1.f/(1.f + __expf(-h8[r]));
    out[r] = p;
    out[64+r] = 0.f;
  }
}

extern "C" void kernel_launch(void* const* d_in, const int* in_sizes, int n_in,
                              void* d_out, int out_size, void* d_ws, size_t ws_size,
                              hipStream_t stream)
{
  const float* x_p1   = (const float*)d_in[0];
  const float* x_p2   = (const float*)d_in[1];
  const float* x_full = (const float*)d_in[2];
  const float* ea_p1  = (const float*)d_in[3];
  const float* ea_p2  = (const float*)d_in[4];
  const float* ea_full= (const float*)d_in[5];
  const int* ei_p1  = (const int*)d_in[6];
  const int* ei_p2  = (const int*)d_in[7];
  const int* ei_full= (const int*)d_in[8];
  const int* route_p1 = (const int*)d_in[9];
  const int* route_p2 = (const int*)d_in[10];
  const float *Wl1=(const float*)d_in[11], *Wr1=(const float*)d_in[12], *We1=(const float*)d_in[13], *att1=(const float*)d_in[14], *b1=(const float*)d_in[15];
  const float *Wl2=(const float*)d_in[16], *Wr2=(const float*)d_in[17], *We2=(const float*)d_in[18], *att2=(const float*)d_in[19], *b2=(const float*)d_in[20];
  const float *Wl3=(const float*)d_in[21], *Wr3=(const float*)d_in[22], *We3=(const float*)d_in[23], *att3=(const float*)d_in[24], *b3=(const float*)d_in[25];
  const float *bng=(const float*)d_in[26], *bnb=(const float*)d_in[27], *png=(const float*)d_in[28], *pnb=(const float*)d_in[29];
  const float *W[8], *Cb[8];
  for (int i=0;i<8;i++){ W[i]=(const float*)d_in[30+2*i]; Cb[i]=(const float*)d_in[31+2*i]; }

  char* w = (char*)d_ws;
  size_t off = 0;
  auto alloc = [&](size_t bytes)->char*{ char* p = w + off; off += (bytes + 255) & ~(size_t)255; return p; };
  u16* P1bf = (u16*)alloc((size_t)NN*512*2);
  u16* P2bf = (u16*)alloc((size_t)NN*512*2);
  u16* FGbf = (u16*)alloc((size_t)NN*512*2);
  char* BIG = alloc((size_t)NN*2048*2);           // phase1: XL|XR|EXf  phase3: CAT
  u16*   XLbf = (u16*)BIG;
  u16*   XRbf = (u16*)(BIG + (size_t)NN*512*2);
  float* EXf  = (float*)(BIG + (size_t)NN*1024*2);
  u16*   CATbf= (u16*)BIG;
  float* EX2 = (float*)alloc((size_t)EPAR*8*4);
  float* st1 = (float*)alloc(1024*4);
  float* st2 = (float*)alloc(1024*4);
  float* stF = (float*)alloc(1024*4);
  float* rs1 = (float*)alloc(64*1024*4);
  float* rs2 = (float*)alloc(64*1024*4);
  float* PTOP= (float*)alloc(64*4096*4);
  float* H0  = (float*)alloc(64*4096*4);
  float* H1  = (float*)alloc(64*4096*4);
  float* PART= (float*)alloc((size_t)8*64*2048*4);
  int* cnt = (int*)alloc(NN*4);
  int* wp  = (int*)alloc(NN*4);
  int* rpF = (int*)alloc((NN+1)*4);
  int* rp1 = (int*)alloc((NN+1)*4);
  int* rp2 = (int*)alloc((NN+1)*4);
  int* eixF= (int*)alloc((size_t)EFULL*4);
  int* eix1= (int*)alloc((size_t)EPAR*4);
  int* eix2= (int*)alloc((size_t)EPAR*4);
  int* rr1 = (int*)alloc(65*4);
  int* rr2 = (int*)alloc(65*4);
  int* nix1= (int*)alloc(NN*4);
  int* nix2= (int*)alloc(NN*4);
  if (ws_size < off){ k_fail<<<1,128,0,stream>>>((float*)d_out); return; }

  // ---- CSR builds (edges by dst) ----
  auto build_csr = [&](const int* dstp, int E, int* rp, int* eix){
    hipMemsetAsync(cnt, 0, NN*4, stream);
    k_count<<<(E+255)/256, 256, 0, stream>>>(dstp, cnt, E);
    k_scan <<<1, 1024, 0, stream>>>(cnt, rp, wp);
    k_fill <<<(E+255)/256, 256, 0, stream>>>(dstp, wp, eix, E);
  };
  build_csr(ei_full+EFULL, EFULL, rpF, eixF);
  build_csr(ei_p1+EPAR,   EPAR,  rp1, eix1);
  build_csr(ei_p2+EPAR,   EPAR,  rp2, eix2);

  // ---- route CSR (nodes by route) ----
  auto build_route = [&](const int* route, int* rrp, int* nix){
    hipMemsetAsync(cnt, 0, 64*4, stream);
    k_count <<<(NN+255)/256, 256, 0, stream>>>(route, cnt, NN);
    k_scan64<<<1, 64, 0, stream>>>(cnt, rrp, wp);
    k_fill  <<<(NN+255)/256, 256, 0, stream>>>(route, wp, nix, NN);
  };
  build_route(route_p1, rr1, nix1);
  build_route(route_p2, rr2, nix2);

  // ---- layer-1 GAT (three graphs, sequential, shared XL/XR/EX temps) ----
  auto gat1 = [&](const float* x, const int* ei, const float* ea, const int* rp, const int* eix,
                  const float* Wl, const float* Wr, const float* We, const float* att, const float* bias,
                  u16* out, int E){
    k_xw   <<<dim3(NN,2), 256, 0, stream>>>(x, Wl, Wr, XLbf, XRbf);
    k_edge1<<<(E+3)/4,  256, 0, stream>>>(ei, ea, We, att, XLbf, XRbf, EXf, E);
    k_agg1 <<<(NN+3)/4, 256, 0, stream>>>(ei, rp, eix, EXf, XLbf, bias, out, E);
  };
  gat1(x_full, ei_full, ea_full, rpF, eixF, Wl2, Wr2, We2, att2, b2, FGbf, EFULL);
  gat1(x_p1,   ei_p1,   ea_p1,   rp1, eix1, Wl1, Wr1, We1, att1, b1, P1bf, EPAR);
  gat1(x_p2,   ei_p2,   ea_p2,   rp2, eix2, Wl1, Wr1, We1, att1, b1, P2bf, EPAR);

  // ---- BatchNorm (batch stats) applied in place; FG half normalized once ----
  hipMemsetAsync(st1, 0, 1024*4, stream);
  hipMemsetAsync(st2, 0, 1024*4, stream);
  hipMemsetAsync(stF, 0, 1024*4, stream);
  k_bnstats<<<dim3(8,16), 256, 0, stream>>>(P1bf, st1);
  k_bnstats<<<dim3(8,16), 256, 0, stream>>>(P2bf, st2);
  k_bnstats<<<dim3(8,16), 256, 0, stream>>>(FGbf, stF);
  int nbn = (NN*512+255)/256;
  k_bnapply<<<nbn, 256, 0, stream>>>(P1bf, st1, bng, bnb, 0);
  k_bnapply<<<nbn, 256, 0, stream>>>(P2bf, st2, bng, bnb, 0);
  k_bnapply<<<nbn, 256, 0, stream>>>(FGbf, stF, bng, bnb, 512);

  // ---- layer-2 GAT + fused route pooling, per parent ----
  auto layer2 = [&](const u16* Pbf, const int* ei, const float* ea, const int* rp, const int* eix,
                    const int* rrp, const int* nix, float* rs){
    k_gemm <<<dim3((NN+127)/128, 16), 256, 0, stream>>>(Pbf, FGbf, Wl3, Wr3, CATbf, NN);
    k_edge2<<<(EPAR+3)/4, 256, 0, stream>>>(ei, ea, We3, att3, CATbf, EX2, EPAR);
    k_agg2pool<<<dim3(64,4), 256, 0, stream>>>(ei, rp, eix, rrp, nix, EX2, CATbf, b3, rs);
  };
  layer2(P1bf, ei_p1, ea_p1, rp1, eix1, rr1, nix1, rs1);
  layer2(P2bf, ei_p2, ea_p2, rp2, eix2, rr2, nix2, rs2);

  // ---- cumsum/route features + pn BN ----
  k_cumsum<<<4, 256, 0, stream>>>(rs1, PTOP, 0);
  k_cumsum<<<4, 256, 0, stream>>>(rs2, PTOP, 2048);
  k_pnbn  <<<16, 256, 0, stream>>>(PTOP, png, pnb, H0);

  // ---- MLP (split-K partials + reduce) ----
  int dims[9] = {4096, 2048, 1024, 512, 256, 128, 64, 32, 1};
  float* bufs[2] = {H0, H1};
  for (int i=0;i<8;i++){
    int Ci = dims[i], Co = dims[i+1];
    int SK = (Ci + KC - 1)/KC;
    k_mlp_part<<<dim3((Co+63)/64, SK), 256, 0, stream>>>(bufs[i&1], W[i], PART, Ci, Co);
    k_mlp_red <<<(64*Co+255)/256, 256, 0, stream>>>(PART, Cb[i], bufs[(i+1)&1], Co, SK, (i<7)?1:0);
  }
  k_sigout<<<1, 64, 0, stream>>>(bufs[0], (float*)d_out);
}

// Round 5
// 3294.330 us; speedup vs baseline: 1.4316x; 1.2128x over previous
//
#include <hip/hip_runtime.h>
#include <stdint.h>

typedef unsigned short u16;
typedef unsigned int   u32;
typedef __attribute__((ext_vector_type(8))) short bf16x8;
typedef __attribute__((ext_vector_type(4))) float f32x4;

#define NN    30000
#define EFULL 240000
#define EPAR  30000

__device__ __forceinline__ float b2f(u16 u){ u32 x=((u32)u)<<16; float f; __builtin_memcpy(&f,&x,4); return f; }
__device__ __forceinline__ u16 f2b(float f){ u32 x; __builtin_memcpy(&x,&f,4); x += 0x7fffu + ((x>>16)&1u); return (u16)(x>>16); }

__device__ __forceinline__ void gload_lds16(const u16* g, u16* l){
  __builtin_amdgcn_global_load_lds((const __attribute__((address_space(1))) void*)g,
                                   (__attribute__((address_space(3))) void*)l, 16, 0, 0);
}

// ---------------- sentinel: workspace too small ----------------
__global__ void k_fail(float* out){ int t=threadIdx.x; if(t<128) out[t]=2.0f; }

// ---------------- CSR build ----------------
__global__ void k_count(const int* __restrict__ dstp, int* __restrict__ cnt, int E){
  int e = blockIdx.x*256 + threadIdx.x;
  if (e < E) atomicAdd(&cnt[dstp[e]], 1);
}

__global__ void k_scan(const int* __restrict__ cnt, int* __restrict__ rp, int* __restrict__ wp){
  __shared__ int sums[1024];
  int t = threadIdx.x;
  const int CH = (NN + 1023)/1024; // 30
  int c0 = t*CH;
  int s = 0;
  for (int i=0;i<CH;i++){ int idx=c0+i; s += (idx<NN)? cnt[idx] : 0; }
  sums[t] = s; __syncthreads();
  for (int off=1; off<1024; off<<=1){
    int v = (t>=off)? sums[t-off] : 0;
    __syncthreads();
    sums[t] += v;
    __syncthreads();
  }
  int run = (t==0)? 0 : sums[t-1];
  for (int i=0;i<CH;i++){
    int idx=c0+i;
    if (idx<NN){ rp[idx]=run; wp[idx]=run; run += cnt[idx]; }
  }
  if (t==1023) rp[NN] = sums[1023];
}

__global__ void k_scan64(const int* __restrict__ cnt, int* __restrict__ rp, int* __restrict__ wp){
  if (threadIdx.x==0){
    int run=0;
    for(int i=0;i<64;i++){ rp[i]=run; wp[i]=run; run+=cnt[i]; }
    rp[64]=run;
  }
}

__global__ void k_fill(const int* __restrict__ dstp, int* __restrict__ wp, int* __restrict__ eix, int E){
  int e = blockIdx.x*256 + threadIdx.x;
  if (e < E){ int p = atomicAdd(&wp[dstp[e]], 1); eix[p] = e; }
}

// ---------------- layer-1 x@W (F=16 -> 512), both L and R, bf16 out ----------------
__global__ __launch_bounds__(256) void k_xw(const float* __restrict__ x,
                                            const float* __restrict__ Wl, const float* __restrict__ Wr,
                                            u16* __restrict__ xl, u16* __restrict__ xr){
  int n = blockIdx.x;
  int c = blockIdx.y*256 + threadIdx.x;
  float xv[16];
  #pragma unroll
  for (int k=0;k<16;k++) xv[k] = x[n*16+k];
  float aL=0.f, aR=0.f;
  #pragma unroll
  for (int k=0;k<16;k++){
    aL += xv[k]*Wl[k*512+c];
    aR += xv[k]*Wr[k*512+c];
  }
  xl[(size_t)n*512+c]=f2b(aL); xr[(size_t)n*512+c]=f2b(aR);
}

// ---------------- edge logits dim=512 (wave per edge) ----------------
__global__ __launch_bounds__(256) void k_edge1(const int* __restrict__ ei, const float* __restrict__ ea,
    const float* __restrict__ We, const float* __restrict__ att,
    const u16* __restrict__ xl, const u16* __restrict__ xr,
    float* __restrict__ ex, int E){
  int lane = threadIdx.x & 63;
  int e = blockIdx.x*4 + (threadIdx.x>>6);
  if (e >= E) return;
  int src = ei[e], dst = ei[E+e];
  float eaw = ea[e];
  int j0 = lane*8;
  bf16x8 lv = *(const bf16x8*)(xl + (size_t)src*512 + j0);
  bf16x8 rv = *(const bf16x8*)(xr + (size_t)dst*512 + j0);
  float logit = 0.f;
  #pragma unroll
  for (int j=0;j<8;j++){
    float v = b2f((u16)lv[j]) + b2f((u16)rv[j]) + eaw*We[j0+j];
    v = v > 0.f ? v : 0.2f*v;
    logit += v * att[j0+j];
  }
  logit += __shfl_xor(logit,1);
  logit += __shfl_xor(logit,2);
  logit += __shfl_xor(logit,4);
  if ((lane&7)==0) ex[(size_t)e*8 + (lane>>3)] = __expf(logit);
}

// ---------------- node aggregation dim=512 (wave per node, CSR), bf16 out ----------------
__global__ __launch_bounds__(256) void k_agg1(const int* __restrict__ ei,
    const int* __restrict__ rp, const int* __restrict__ eix,
    const float* __restrict__ ex, const u16* __restrict__ xl,
    const float* __restrict__ bias, u16* __restrict__ out, int E){
  int lane = threadIdx.x & 63;
  int n = blockIdx.x*4 + (threadIdx.x>>6);
  if (n >= NN) return;
  int r0 = rp[n], r1 = rp[n+1];
  float den = 0.f;
  for (int i = r0 + (lane>>3); i < r1; i += 8)
    den += ex[(size_t)eix[i]*8 + (lane&7)];
  den += __shfl_xor(den,8); den += __shfl_xor(den,16); den += __shfl_xor(den,32);
  float myden = __shfl(den, lane>>3);
  float inv = 1.f/(myden + 1e-16f);
  int j0 = lane*8;
  float acc[8] = {0,0,0,0,0,0,0,0};
  for (int i=r0;i<r1;i++){
    int e = eix[i];
    float a = ex[(size_t)e*8 + (lane>>3)] * inv;
    bf16x8 v = *(const bf16x8*)(xl + (size_t)ei[e]*512 + j0);
    #pragma unroll
    for (int j=0;j<8;j++) acc[j] += a*b2f((u16)v[j]);
  }
  #pragma unroll
  for (int j=0;j<8;j++) out[(size_t)n*512 + j0 + j] = f2b(acc[j] + bias[j0+j]);
}

// ---------------- BN stats (per column over 30000 rows, 512 cols) ----------------
__global__ __launch_bounds__(256) void k_bnstats(const u16* __restrict__ P, float* __restrict__ st){
  int c = blockIdx.x*64 + (threadIdx.x&63);
  int rs0 = blockIdx.y*4 + (threadIdx.x>>6); // 64 row strides total
  float s=0.f, q=0.f;
  for (int r=rs0; r<NN; r+=64){ float v = b2f(P[(size_t)r*512+c]); s+=v; q+=v*v; }
  atomicAdd(&st[c], s);
  atomicAdd(&st[512+c], q);
}

// ---------------- BN apply in-place (bf16), coff selects gamma/beta columns ----------------
__global__ __launch_bounds__(256) void k_bnapply(u16* __restrict__ P, const float* __restrict__ st,
    const float* __restrict__ g, const float* __restrict__ b, int coff){
  int idx = blockIdx.x*256 + threadIdx.x;
  if (idx >= NN*512) return;
  int c = idx & 511;
  const float invN = 1.f/30000.f;
  float mu = st[c]*invN;
  float var = st[512+c]*invN - mu*mu;
  float r = rsqrtf(var + 1e-5f);
  float v = b2f(P[idx]);
  P[idx] = f2b((v-mu)*r*g[coff+c] + b[coff+c]);
}

// ---------------- B pre-transpose + bf16: Bt[2048][1024], Bt[n][k] = W[k][n&1023] ----------------
__global__ __launch_bounds__(256) void k_bt(const float* __restrict__ B0, const float* __restrict__ B1,
                                            u16* __restrict__ Bt){
  __shared__ u16 tile[64][65];
  int bk = blockIdx.x;        // k tile
  int bn = blockIdx.y;        // n tile
  const float* B = blockIdx.z ? B1 : B0;
  int nb = blockIdx.z*1024;
  for (int i = threadIdx.x; i < 64*64; i += 256){
    int r = i>>6, c = i&63;
    tile[c][r] = f2b(B[(size_t)(bk*64+r)*1024 + bn*64 + c]);
  }
  __syncthreads();
  for (int i = threadIdx.x; i < 64*64; i += 256){
    int r = i>>6, c = i&63;
    Bt[(size_t)(nb + bn*64 + r)*1024 + bk*64 + c] = tile[r][c];
  }
}

// ---------------- MFMA GEMM (m97-style): CAT[M,2048] = [A0|A1][M,1024] @ Bt^T, bf16 out ----------------
__global__ __launch_bounds__(256) void k_gemm(const u16* __restrict__ A0, const u16* __restrict__ A1,
    const u16* __restrict__ Bt, u16* __restrict__ C, int M){
  __shared__ u16 As[128*64];
  __shared__ u16 Bs[128*64];
  int n0 = blockIdx.x*128;
  int m0 = blockIdx.y*128;
  int t = threadIdx.x;
  int wave = t>>6, lane = t&63;
  int wm = (wave>>1)*64, wn = (wave&1)*64;
  int rr = lane&15, kq = (lane>>4)*8;
  int srow = t>>3;            // 0..31 (== wave*8 + (lane>>3))
  int scol = (t&7)*8;         // lane-contiguous 16B chunks
  f32x4 acc[4][4];
  #pragma unroll
  for (int m=0;m<4;m++)
    #pragma unroll
    for (int n=0;n<4;n++){ acc[m][n][0]=0.f; acc[m][n][1]=0.f; acc[m][n][2]=0.f; acc[m][n][3]=0.f; }
  for (int k0=0; k0<1024; k0+=64){
    const u16* Ap = (k0 < 512) ? A0 : A1;
    int kc = k0 & 511;
    #pragma unroll
    for (int i=0;i<4;i++){
      int row = i*32 + srow;
      gload_lds16(Ap + (size_t)(m0+row)*512 + kc + scol, As + row*64 + scol);
    }
    #pragma unroll
    for (int i=0;i<4;i++){
      int row = i*32 + srow;
      gload_lds16(Bt + (size_t)(n0+row)*1024 + k0 + scol, Bs + row*64 + scol);
    }
    __syncthreads();
    #pragma unroll
    for (int ks=0; ks<2; ks++){
      bf16x8 af[4], bb[4];
      #pragma unroll
      for (int m=0;m<4;m++) af[m] = *(const bf16x8*)(&As[(wm + m*16 + rr)*64 + ks*32 + kq]);
      #pragma unroll
      for (int n=0;n<4;n++) bb[n] = *(const bf16x8*)(&Bs[(wn + n*16 + rr)*64 + ks*32 + kq]);
      #pragma unroll
      for (int m=0;m<4;m++)
        #pragma unroll
        for (int n=0;n<4;n++)
          acc[m][n] = __builtin_amdgcn_mfma_f32_16x16x32_bf16(af[m], bb[n], acc[m][n], 0, 0, 0);
    }
    __syncthreads();
  }
  int rq = (lane>>4)*4;
  #pragma unroll
  for (int m=0;m<4;m++)
    #pragma unroll
    for (int n=0;n<4;n++)
      #pragma unroll
      for (int j=0;j<4;j++){
        int row = m0 + wm + m*16 + rq + j;
        int col = n0 + wn + n*16 + rr;
        if (row < M) C[(size_t)row*2048 + col] = f2b(acc[m][n][j]);
      }
}

// ---------------- edge logits dim=1024 (layer 2, CAT bf16) ----------------
__global__ __launch_bounds__(256) void k_edge2(const int* __restrict__ ei, const float* __restrict__ ea,
    const float* __restrict__ We, const float* __restrict__ att,
    const u16* __restrict__ CAT, float* __restrict__ ex, int E){
  int lane = threadIdx.x & 63;
  int e = blockIdx.x*4 + (threadIdx.x>>6);
  if (e >= E) return;
  int src = ei[e], dst = ei[E+e];
  float eaw = ea[e];
  int j0 = lane*16;
  bf16x8 l0 = *(const bf16x8*)(CAT + (size_t)src*2048 + j0);
  bf16x8 l1 = *(const bf16x8*)(CAT + (size_t)src*2048 + j0 + 8);
  bf16x8 r0 = *(const bf16x8*)(CAT + (size_t)dst*2048 + 1024 + j0);
  bf16x8 r1 = *(const bf16x8*)(CAT + (size_t)dst*2048 + 1024 + j0 + 8);
  float logit = 0.f;
  #pragma unroll
  for (int j=0;j<16;j++){
    float lvj = b2f((u16)((j<8)? l0[j] : l1[j-8]));
    float rvj = b2f((u16)((j<8)? r0[j] : r1[j-8]));
    float v = lvj + rvj + eaw*We[j0+j];
    v = v > 0.f ? v : 0.2f*v;
    logit += v * att[j0+j];
  }
  logit += __shfl_xor(logit,1);
  logit += __shfl_xor(logit,2);
  logit += __shfl_xor(logit,4);
  if ((lane&7)==0) ex[(size_t)e*8 + (lane>>3)] = __expf(logit);
}

// ---------------- fused layer-2 aggregation + route pooling ----------------
__global__ __launch_bounds__(256) void k_agg2pool(const int* __restrict__ ei,
    const int* __restrict__ rp, const int* __restrict__ eix,
    const int* __restrict__ rrp, const int* __restrict__ nix,
    const float* __restrict__ ex, const u16* __restrict__ CAT,
    const float* __restrict__ b3, float* __restrict__ rs){
  int r = blockIdx.x;                      // 0..63
  int c = blockIdx.y*256 + threadIdx.x;    // 0..1023
  int h = c >> 7;
  int i0 = rrp[r], i1 = rrp[r+1];
  float acc = 0.f;
  for (int i=i0;i<i1;i++){
    int n = nix[i];
    int e0 = rp[n], e1 = rp[n+1];
    float den = 0.f;
    for (int t=e0;t<e1;t++) den += ex[(size_t)eix[t]*8 + h];
    float inv = 1.f/(den + 1e-16f);
    for (int t=e0;t<e1;t++){
      int e = eix[t];
      acc += ex[(size_t)e*8 + h] * inv * b2f(CAT[(size_t)ei[e]*2048 + c]);
    }
  }
  rs[r*1024 + c] = acc + (float)(i1-i0)*b3[c];
}

// ---------------- cumsum over routes -> ptop halves ----------------
__global__ void k_cumsum(const float* __restrict__ rs, float* __restrict__ ptop, int colbase){
  int c = blockIdx.x*256 + threadIdx.x; // 1024 cols
  float tot = 0.f;
  for (int r=0;r<64;r++) tot += rs[r*1024+c];
  float cs = 0.f;
  for (int r=0;r<64;r++){
    cs += rs[r*1024+c];
    ptop[r*4096 + colbase + c] = cs;
    ptop[r*4096 + colbase + 1024 + c] = tot - cs;
  }
}

// ---------------- BN over 64 routes (per column) ----------------
__global__ void k_pnbn(const float* __restrict__ ptop, const float* __restrict__ g, const float* __restrict__ b,
                       float* __restrict__ h){
  int c = blockIdx.x*256 + threadIdx.x; // 4096 cols
  float s=0.f, q=0.f;
  for (int r=0;r<64;r++){ float v = ptop[r*4096+c]; s+=v; q+=v*v; }
  float mu = s*(1.f/64.f), var = q*(1.f/64.f)-mu*mu;
  float rr = rsqrtf(var + 1e-5f);
  float gg = g[c], bb = b[c];
  for (int r=0;r<64;r++) h[r*4096+c] = (ptop[r*4096+c]-mu)*rr*gg + bb;
}

// ---------------- MLP split-K partials: PART[sk][64][Co] ----------------
#define KC 512
__global__ __launch_bounds__(256) void k_mlp_part(const float* __restrict__ In,
    const float* __restrict__ W, float* __restrict__ PART, int Ci, int Co){
  __shared__ float tin[64*64]; // 16 KiB: rows x ksub
  int c  = blockIdx.x*64 + (threadIdx.x&63);
  int rg = threadIdx.x>>6;     // 0..3
  int k0 = blockIdx.y*KC, k1 = min(Ci, k0+KC);
  float acc[16];
  #pragma unroll
  for (int j=0;j<16;j++) acc[j]=0.f;
  for (int ks=k0; ks<k1; ks+=64){
    int kw = min(64, k1-ks);
    __syncthreads();
    for (int i=threadIdx.x;i<64*64;i+=256){
      int r=i>>6, k=i&63;
      tin[i] = (k<kw)? In[(size_t)r*Ci + ks + k] : 0.f;
    }
    __syncthreads();
    if (c < Co){
      for (int k=0;k<kw;k+=4){
        float4 w4;
        w4.x = W[(size_t)(ks+k  )*Co + c];
        w4.y = W[(size_t)(ks+k+1)*Co + c];
        w4.z = W[(size_t)(ks+k+2)*Co + c];
        w4.w = W[(size_t)(ks+k+3)*Co + c];
        #pragma unroll
        for (int j=0;j<16;j++){
          float4 t4 = *(const float4*)(&tin[(rg*16+j)*64 + k]); // broadcast read
          acc[j] += t4.x*w4.x + t4.y*w4.y + t4.z*w4.z + t4.w*w4.w;
        }
      }
    }
  }
  if (c < Co){
    float* P = PART + (size_t)blockIdx.y*64*Co;
    #pragma unroll
    for (int j=0;j<16;j++)
      P[(size_t)(rg*16+j)*Co + c] = acc[j];
  }
}

// ---------------- MLP reduce: Out = act(sum_sk PART + bias) ----------------
__global__ void k_mlp_red(const float* __restrict__ PART, const float* __restrict__ bias,
                          float* __restrict__ Out, int Co, int SK, int act){
  int idx = blockIdx.x*256 + threadIdx.x;
  if (idx >= 64*Co) return;
  int c = idx % Co;
  float s = bias[c];
  for (int sk=0; sk<SK; sk++) s += PART[(size_t)sk*64*Co + idx];
  if (act) s = s>0.f ? s : 0.01f*s;
  Out[idx] = s;
}

// ---------------- sigmoid + output (f32) ----------------
__global__ void k_sigout(const float* __restrict__ h8, float* __restrict__ out){
  int r = threadIdx.x;
  if (r < 64){
    float p = 1.f/(1.f + __expf(-h8[r]));
    out[r] = p;
    out[64+r] = 0.f;
  }
}

extern "C" void kernel_launch(void* const* d_in, const int* in_sizes, int n_in,
                              void* d_out, int out_size, void* d_ws, size_t ws_size,
                              hipStream_t stream)
{
  const float* x_p1   = (const float*)d_in[0];
  const float* x_p2   = (const float*)d_in[1];
  const float* x_full = (const float*)d_in[2];
  const float* ea_p1  = (const float*)d_in[3];
  const float* ea_p2  = (const float*)d_in[4];
  const float* ea_full= (const float*)d_in[5];
  const int* ei_p1  = (const int*)d_in[6];
  const int* ei_p2  = (const int*)d_in[7];
  const int* ei_full= (const int*)d_in[8];
  const int* route_p1 = (const int*)d_in[9];
  const int* route_p2 = (const int*)d_in[10];
  const float *Wl1=(const float*)d_in[11], *Wr1=(const float*)d_in[12], *We1=(const float*)d_in[13], *att1=(const float*)d_in[14], *b1=(const float*)d_in[15];
  const float *Wl2=(const float*)d_in[16], *Wr2=(const float*)d_in[17], *We2=(const float*)d_in[18], *att2=(const float*)d_in[19], *b2=(const float*)d_in[20];
  const float *Wl3=(const float*)d_in[21], *Wr3=(const float*)d_in[22], *We3=(const float*)d_in[23], *att3=(const float*)d_in[24], *b3=(const float*)d_in[25];
  const float *bng=(const float*)d_in[26], *bnb=(const float*)d_in[27], *png=(const float*)d_in[28], *pnb=(const float*)d_in[29];
  const float *W[8], *Cb[8];
  for (int i=0;i<8;i++){ W[i]=(const float*)d_in[30+2*i]; Cb[i]=(const float*)d_in[31+2*i]; }

  char* w = (char*)d_ws;
  size_t off = 0;
  auto alloc = [&](size_t bytes)->char*{ char* p = w + off; off += (bytes + 255) & ~(size_t)255; return p; };
  u16* P1bf = (u16*)alloc((size_t)NN*512*2);
  u16* P2bf = (u16*)alloc((size_t)NN*512*2);
  u16* FGbf = (u16*)alloc((size_t)NN*512*2);
  char* BIG = alloc((size_t)NN*2048*2);           // phase1: XL|XR|EXf  phase3: CAT
  u16*   XLbf = (u16*)BIG;
  u16*   XRbf = (u16*)(BIG + (size_t)NN*512*2);
  float* EXf  = (float*)(BIG + (size_t)NN*1024*2);
  u16*   CATbf= (u16*)BIG;
  u16*   Bt   = (u16*)alloc((size_t)2048*1024*2);
  float* EX2 = (float*)alloc((size_t)EPAR*8*4);
  float* st1 = (float*)alloc(1024*4);
  float* st2 = (float*)alloc(1024*4);
  float* stF = (float*)alloc(1024*4);
  float* rs1 = (float*)alloc(64*1024*4);
  float* rs2 = (float*)alloc(64*1024*4);
  float* PTOP= (float*)alloc(64*4096*4);
  float* H0  = (float*)alloc(64*4096*4);
  float* H1  = (float*)alloc(64*4096*4);
  float* PART= (float*)alloc((size_t)8*64*2048*4);
  int* cnt = (int*)alloc(NN*4);
  int* wp  = (int*)alloc(NN*4);
  int* rpF = (int*)alloc((NN+1)*4);
  int* rp1 = (int*)alloc((NN+1)*4);
  int* rp2 = (int*)alloc((NN+1)*4);
  int* eixF= (int*)alloc((size_t)EFULL*4);
  int* eix1= (int*)alloc((size_t)EPAR*4);
  int* eix2= (int*)alloc((size_t)EPAR*4);
  int* rr1 = (int*)alloc(65*4);
  int* rr2 = (int*)alloc(65*4);
  int* nix1= (int*)alloc(NN*4);
  int* nix2= (int*)alloc(NN*4);
  if (ws_size < off){ k_fail<<<1,128,0,stream>>>((float*)d_out); return; }

  // ---- CSR builds (edges by dst) ----
  auto build_csr = [&](const int* dstp, int E, int* rp, int* eix){
    hipMemsetAsync(cnt, 0, NN*4, stream);
    k_count<<<(E+255)/256, 256, 0, stream>>>(dstp, cnt, E);
    k_scan <<<1, 1024, 0, stream>>>(cnt, rp, wp);
    k_fill <<<(E+255)/256, 256, 0, stream>>>(dstp, wp, eix, E);
  };
  build_csr(ei_full+EFULL, EFULL, rpF, eixF);
  build_csr(ei_p1+EPAR,   EPAR,  rp1, eix1);
  build_csr(ei_p2+EPAR,   EPAR,  rp2, eix2);

  // ---- route CSR (nodes by route) ----
  auto build_route = [&](const int* route, int* rrp, int* nix){
    hipMemsetAsync(cnt, 0, 64*4, stream);
    k_count <<<(NN+255)/256, 256, 0, stream>>>(route, cnt, NN);
    k_scan64<<<1, 64, 0, stream>>>(cnt, rrp, wp);
    k_fill  <<<(NN+255)/256, 256, 0, stream>>>(route, wp, nix, NN);
  };
  build_route(route_p1, rr1, nix1);
  build_route(route_p2, rr2, nix2);

  // ---- B pre-transpose for layer-2 GEMM ----
  k_bt<<<dim3(16,16,2), 256, 0, stream>>>(Wl3, Wr3, Bt);

  // ---- layer-1 GAT (three graphs, sequential, shared XL/XR/EX temps) ----
  auto gat1 = [&](const float* x, const int* ei, const float* ea, const int* rp, const int* eix,
                  const float* Wl, const float* Wr, const float* We, const float* att, const float* bias,
                  u16* out, int E){
    k_xw   <<<dim3(NN,2), 256, 0, stream>>>(x, Wl, Wr, XLbf, XRbf);
    k_edge1<<<(E+3)/4,  256, 0, stream>>>(ei, ea, We, att, XLbf, XRbf, EXf, E);
    k_agg1 <<<(NN+3)/4, 256, 0, stream>>>(ei, rp, eix, EXf, XLbf, bias, out, E);
  };
  gat1(x_full, ei_full, ea_full, rpF, eixF, Wl2, Wr2, We2, att2, b2, FGbf, EFULL);
  gat1(x_p1,   ei_p1,   ea_p1,   rp1, eix1, Wl1, Wr1, We1, att1, b1, P1bf, EPAR);
  gat1(x_p2,   ei_p2,   ea_p2,   rp2, eix2, Wl1, Wr1, We1, att1, b1, P2bf, EPAR);

  // ---- BatchNorm (batch stats) applied in place; FG half normalized once ----
  hipMemsetAsync(st1, 0, 1024*4, stream);
  hipMemsetAsync(st2, 0, 1024*4, stream);
  hipMemsetAsync(stF, 0, 1024*4, stream);
  k_bnstats<<<dim3(8,16), 256, 0, stream>>>(P1bf, st1);
  k_bnstats<<<dim3(8,16), 256, 0, stream>>>(P2bf, st2);
  k_bnstats<<<dim3(8,16), 256, 0, stream>>>(FGbf, stF);
  int nbn = (NN*512+255)/256;
  k_bnapply<<<nbn, 256, 0, stream>>>(P1bf, st1, bng, bnb, 0);
  k_bnapply<<<nbn, 256, 0, stream>>>(P2bf, st2, bng, bnb, 0);
  k_bnapply<<<nbn, 256, 0, stream>>>(FGbf, stF, bng, bnb, 512);

  // ---- layer-2 GAT + fused route pooling, per parent ----
  auto layer2 = [&](const u16* Pbf, const int* ei, const float* ea, const int* rp, const int* eix,
                    const int* rrp, const int* nix, float* rs){
    k_gemm <<<dim3(16, (NN+127)/128), 256, 0, stream>>>(Pbf, FGbf, Bt, CATbf, NN);
    k_edge2<<<(EPAR+3)/4, 256, 0, stream>>>(ei, ea, We3, att3, CATbf, EX2, EPAR);
    k_agg2pool<<<dim3(64,4), 256, 0, stream>>>(ei, rp, eix, rrp, nix, EX2, CATbf, b3, rs);
  };
  layer2(P1bf, ei_p1, ea_p1, rp1, eix1, rr1, nix1, rs1);
  layer2(P2bf, ei_p2, ea_p2, rp2, eix2, rr2, nix2, rs2);

  // ---- cumsum/route features + pn BN ----
  k_cumsum<<<4, 256, 0, stream>>>(rs1, PTOP, 0);
  k_cumsum<<<4, 256, 0, stream>>>(rs2, PTOP, 2048);
  k_pnbn  <<<16, 256, 0, stream>>>(PTOP, png, pnb, H0);

  // ---- MLP (split-K partials + reduce) ----
  int dims[9] = {4096, 2048, 1024, 512, 256, 128, 64, 32, 1};
  float* bufs[2] = {H0, H1};
  for (int i=0;i<8;i++){
    int Ci = dims[i], Co = dims[i+1];
    int SK = (Ci + KC - 1)/KC;
    k_mlp_part<<<dim3((Co+63)/64, SK), 256, 0, stream>>>(bufs[i&1], W[i], PART, Ci, Co);
    k_mlp_red <<<(64*Co+255)/256, 256, 0, stream>>>(PART, Cb[i], bufs[(i+1)&1], Co, SK, (i<7)?1:0);
  }
  k_sigout<<<1, 64, 0, stream>>>(bufs[0], (float*)d_out);
}

// Round 6
// 2628.613 us; speedup vs baseline: 1.7942x; 1.2533x over previous
//
#include <hip/hip_runtime.h>
#include <stdint.h>

typedef unsigned short u16;
typedef unsigned int   u32;
typedef __attribute__((ext_vector_type(8))) short bf16x8;
typedef __attribute__((ext_vector_type(4))) float f32x4;

#define NN    30000
#define EFULL 240000
#define EPAR  30000

__device__ __forceinline__ float b2f(u16 u){ u32 x=((u32)u)<<16; float f; __builtin_memcpy(&f,&x,4); return f; }
__device__ __forceinline__ u16 f2b(float f){ u32 x; __builtin_memcpy(&x,&f,4); x += 0x7fffu + ((x>>16)&1u); return (u16)(x>>16); }

__device__ __forceinline__ void gload_lds16(const u16* g, u16* l){
  __builtin_amdgcn_global_load_lds((const __attribute__((address_space(1))) void*)g,
                                   (__attribute__((address_space(3))) void*)l, 16, 0, 0);
}

// ---------------- sentinel: workspace too small ----------------
__global__ void k_fail(float* out){ int t=threadIdx.x; if(t<128) out[t]=2.0f; }

// ---------------- CSR build ----------------
__global__ void k_count(const int* __restrict__ dstp, int* __restrict__ cnt, int E){
  int e = blockIdx.x*256 + threadIdx.x;
  if (e < E) atomicAdd(&cnt[dstp[e]], 1);
}

__global__ void k_scan(const int* __restrict__ cnt, int* __restrict__ rp, int* __restrict__ wp){
  __shared__ int sums[1024];
  int t = threadIdx.x;
  const int CH = (NN + 1023)/1024; // 30
  int c0 = t*CH;
  int s = 0;
  for (int i=0;i<CH;i++){ int idx=c0+i; s += (idx<NN)? cnt[idx] : 0; }
  sums[t] = s; __syncthreads();
  for (int off=1; off<1024; off<<=1){
    int v = (t>=off)? sums[t-off] : 0;
    __syncthreads();
    sums[t] += v;
    __syncthreads();
  }
  int run = (t==0)? 0 : sums[t-1];
  for (int i=0;i<CH;i++){
    int idx=c0+i;
    if (idx<NN){ rp[idx]=run; wp[idx]=run; run += cnt[idx]; }
  }
  if (t==1023) rp[NN] = sums[1023];
}

__global__ void k_scan64(const int* __restrict__ cnt, int* __restrict__ rp, int* __restrict__ wp){
  if (threadIdx.x==0){
    int run=0;
    for(int i=0;i<64;i++){ rp[i]=run; wp[i]=run; run+=cnt[i]; }
    rp[64]=run;
  }
}

__global__ void k_fill(const int* __restrict__ dstp, int* __restrict__ wp, int* __restrict__ eix, int E){
  int e = blockIdx.x*256 + threadIdx.x;
  if (e < E){ int p = atomicAdd(&wp[dstp[e]], 1); eix[p] = e; }
}

// route-of-dst edge CSR helpers
__global__ void k_counte(const int* __restrict__ dstp, const int* __restrict__ route,
                         int* __restrict__ cnt, int E){
  int e = blockIdx.x*256 + threadIdx.x;
  if (e < E) atomicAdd(&cnt[route[dstp[e]]], 1);
}
__global__ void k_fille(const int* __restrict__ dstp, const int* __restrict__ route,
                        int* __restrict__ wp, int* __restrict__ reix, int E){
  int e = blockIdx.x*256 + threadIdx.x;
  if (e < E){ int p = atomicAdd(&wp[route[dstp[e]]], 1); reix[p] = e; }
}

// ---------------- layer-1 x@W (F=16 -> 512), both L and R, bf16 out ----------------
__global__ __launch_bounds__(256) void k_xw(const float* __restrict__ x,
                                            const float* __restrict__ Wl, const float* __restrict__ Wr,
                                            u16* __restrict__ xl, u16* __restrict__ xr){
  int n = blockIdx.x;
  int c = blockIdx.y*256 + threadIdx.x;
  float xv[16];
  #pragma unroll
  for (int k=0;k<16;k++) xv[k] = x[n*16+k];
  float aL=0.f, aR=0.f;
  #pragma unroll
  for (int k=0;k<16;k++){
    aL += xv[k]*Wl[k*512+c];
    aR += xv[k]*Wr[k*512+c];
  }
  xl[(size_t)n*512+c]=f2b(aL); xr[(size_t)n*512+c]=f2b(aR);
}

// ---------------- edge logits dim=512 (wave per edge) ----------------
__global__ __launch_bounds__(256) void k_edge1(const int* __restrict__ ei, const float* __restrict__ ea,
    const float* __restrict__ We, const float* __restrict__ att,
    const u16* __restrict__ xl, const u16* __restrict__ xr,
    float* __restrict__ ex, int E){
  int lane = threadIdx.x & 63;
  int e = blockIdx.x*4 + (threadIdx.x>>6);
  if (e >= E) return;
  int src = ei[e], dst = ei[E+e];
  float eaw = ea[e];
  int j0 = lane*8;
  bf16x8 lv = *(const bf16x8*)(xl + (size_t)src*512 + j0);
  bf16x8 rv = *(const bf16x8*)(xr + (size_t)dst*512 + j0);
  float logit = 0.f;
  #pragma unroll
  for (int j=0;j<8;j++){
    float v = b2f((u16)lv[j]) + b2f((u16)rv[j]) + eaw*We[j0+j];
    v = v > 0.f ? v : 0.2f*v;
    logit += v * att[j0+j];
  }
  logit += __shfl_xor(logit,1);
  logit += __shfl_xor(logit,2);
  logit += __shfl_xor(logit,4);
  if ((lane&7)==0) ex[(size_t)e*8 + (lane>>3)] = __expf(logit);
}

// ---------------- node aggregation dim=512 (wave per node, CSR), bf16 out ----------------
__global__ __launch_bounds__(256) void k_agg1(const int* __restrict__ ei,
    const int* __restrict__ rp, const int* __restrict__ eix,
    const float* __restrict__ ex, const u16* __restrict__ xl,
    const float* __restrict__ bias, u16* __restrict__ out, int E){
  int lane = threadIdx.x & 63;
  int n = blockIdx.x*4 + (threadIdx.x>>6);
  if (n >= NN) return;
  int r0 = rp[n], r1 = rp[n+1];
  float den = 0.f;
  for (int i = r0 + (lane>>3); i < r1; i += 8)
    den += ex[(size_t)eix[i]*8 + (lane&7)];
  den += __shfl_xor(den,8); den += __shfl_xor(den,16); den += __shfl_xor(den,32);
  float myden = __shfl(den, lane>>3);
  float inv = 1.f/(myden + 1e-16f);
  int j0 = lane*8;
  float acc[8] = {0,0,0,0,0,0,0,0};
  for (int i=r0;i<r1;i++){
    int e = eix[i];
    float a = ex[(size_t)e*8 + (lane>>3)] * inv;
    bf16x8 v = *(const bf16x8*)(xl + (size_t)ei[e]*512 + j0);
    #pragma unroll
    for (int j=0;j<8;j++) acc[j] += a*b2f((u16)v[j]);
  }
  #pragma unroll
  for (int j=0;j<8;j++) out[(size_t)n*512 + j0 + j] = f2b(acc[j] + bias[j0+j]);
}

// ---------------- BN stats (per column over 30000 rows, 512 cols) ----------------
__global__ __launch_bounds__(256) void k_bnstats(const u16* __restrict__ P, float* __restrict__ st){
  int c = blockIdx.x*64 + (threadIdx.x&63);
  int rs0 = blockIdx.y*4 + (threadIdx.x>>6); // 64 row strides total
  float s=0.f, q=0.f;
  for (int r=rs0; r<NN; r+=64){ float v = b2f(P[(size_t)r*512+c]); s+=v; q+=v*v; }
  atomicAdd(&st[c], s);
  atomicAdd(&st[512+c], q);
}

// ---------------- BN apply in-place (bf16), coff selects gamma/beta columns ----------------
__global__ __launch_bounds__(256) void k_bnapply(u16* __restrict__ P, const float* __restrict__ st,
    const float* __restrict__ g, const float* __restrict__ b, int coff){
  int idx = blockIdx.x*256 + threadIdx.x;
  if (idx >= NN*512) return;
  int c = idx & 511;
  const float invN = 1.f/30000.f;
  float mu = st[c]*invN;
  float var = st[512+c]*invN - mu*mu;
  float r = rsqrtf(var + 1e-5f);
  float v = b2f(P[idx]);
  P[idx] = f2b((v-mu)*r*g[coff+c] + b[coff+c]);
}

// ---------------- B pre-transpose + bf16: Bt[2048][1024], Bt[n][k] = W[k][n&1023] ----------------
__global__ __launch_bounds__(256) void k_bt(const float* __restrict__ B0, const float* __restrict__ B1,
                                            u16* __restrict__ Bt){
  __shared__ u16 tile[64][65];
  int bk = blockIdx.x;        // k tile
  int bn = blockIdx.y;        // n tile
  const float* B = blockIdx.z ? B1 : B0;
  int nb = blockIdx.z*1024;
  for (int i = threadIdx.x; i < 64*64; i += 256){
    int r = i>>6, c = i&63;
    tile[c][r] = f2b(B[(size_t)(bk*64+r)*1024 + bn*64 + c]);
  }
  __syncthreads();
  for (int i = threadIdx.x; i < 64*64; i += 256){
    int r = i>>6, c = i&63;
    Bt[(size_t)(nb + bn*64 + r)*1024 + bk*64 + c] = tile[r][c];
  }
}

// ---------------- MFMA GEMM (m97-style): CAT[M,2048] = [A0|A1][M,1024] @ Bt^T, bf16 out ----------------
__global__ __launch_bounds__(256) void k_gemm(const u16* __restrict__ A0, const u16* __restrict__ A1,
    const u16* __restrict__ Bt, u16* __restrict__ C, int M){
  __shared__ u16 As[128*64];
  __shared__ u16 Bs[128*64];
  int n0 = blockIdx.x*128;
  int m0 = blockIdx.y*128;
  int t = threadIdx.x;
  int wave = t>>6, lane = t&63;
  int wm = (wave>>1)*64, wn = (wave&1)*64;
  int rr = lane&15, kq = (lane>>4)*8;
  int srow = t>>3;            // 0..31
  int scol = (t&7)*8;
  f32x4 acc[4][4];
  #pragma unroll
  for (int m=0;m<4;m++)
    #pragma unroll
    for (int n=0;n<4;n++){ acc[m][n][0]=0.f; acc[m][n][1]=0.f; acc[m][n][2]=0.f; acc[m][n][3]=0.f; }
  for (int k0=0; k0<1024; k0+=64){
    const u16* Ap = (k0 < 512) ? A0 : A1;
    int kc = k0 & 511;
    #pragma unroll
    for (int i=0;i<4;i++){
      int row = i*32 + srow;
      gload_lds16(Ap + (size_t)(m0+row)*512 + kc + scol, As + row*64 + scol);
    }
    #pragma unroll
    for (int i=0;i<4;i++){
      int row = i*32 + srow;
      gload_lds16(Bt + (size_t)(n0+row)*1024 + k0 + scol, Bs + row*64 + scol);
    }
    __syncthreads();
    #pragma unroll
    for (int ks=0; ks<2; ks++){
      bf16x8 af[4], bb[4];
      #pragma unroll
      for (int m=0;m<4;m++) af[m] = *(const bf16x8*)(&As[(wm + m*16 + rr)*64 + ks*32 + kq]);
      #pragma unroll
      for (int n=0;n<4;n++) bb[n] = *(const bf16x8*)(&Bs[(wn + n*16 + rr)*64 + ks*32 + kq]);
      #pragma unroll
      for (int m=0;m<4;m++)
        #pragma unroll
        for (int n=0;n<4;n++)
          acc[m][n] = __builtin_amdgcn_mfma_f32_16x16x32_bf16(af[m], bb[n], acc[m][n], 0, 0, 0);
    }
    __syncthreads();
  }
  int rq = (lane>>4)*4;
  #pragma unroll
  for (int m=0;m<4;m++)
    #pragma unroll
    for (int n=0;n<4;n++)
      #pragma unroll
      for (int j=0;j<4;j++){
        int row = m0 + wm + m*16 + rq + j;
        int col = n0 + wn + n*16 + rr;
        if (row < M) C[(size_t)row*2048 + col] = f2b(acc[m][n][j]);
      }
}

// ---------------- edge logits dim=1024 (layer 2, CAT bf16) ----------------
__global__ __launch_bounds__(256) void k_edge2(const int* __restrict__ ei, const float* __restrict__ ea,
    const float* __restrict__ We, const float* __restrict__ att,
    const u16* __restrict__ CAT, float* __restrict__ ex, int E){
  int lane = threadIdx.x & 63;
  int e = blockIdx.x*4 + (threadIdx.x>>6);
  if (e >= E) return;
  int src = ei[e], dst = ei[E+e];
  float eaw = ea[e];
  int j0 = lane*16;
  bf16x8 l0 = *(const bf16x8*)(CAT + (size_t)src*2048 + j0);
  bf16x8 l1 = *(const bf16x8*)(CAT + (size_t)src*2048 + j0 + 8);
  bf16x8 r0 = *(const bf16x8*)(CAT + (size_t)dst*2048 + 1024 + j0);
  bf16x8 r1 = *(const bf16x8*)(CAT + (size_t)dst*2048 + 1024 + j0 + 8);
  float logit = 0.f;
  #pragma unroll
  for (int j=0;j<16;j++){
    float lvj = b2f((u16)((j<8)? l0[j] : l1[j-8]));
    float rvj = b2f((u16)((j<8)? r0[j] : r1[j-8]));
    float v = lvj + rvj + eaw*We[j0+j];
    v = v > 0.f ? v : 0.2f*v;
    logit += v * att[j0+j];
  }
  logit += __shfl_xor(logit,1);
  logit += __shfl_xor(logit,2);
  logit += __shfl_xor(logit,4);
  if ((lane&7)==0) ex[(size_t)e*8 + (lane>>3)] = __expf(logit);
}

// ---------------- per-(node,head) inverse denominator ----------------
__global__ void k_den(const int* __restrict__ rp, const int* __restrict__ eix,
                      const float* __restrict__ ex, float* __restrict__ deninv){
  int idx = blockIdx.x*256 + threadIdx.x;
  if (idx >= NN*8) return;
  int n = idx>>3, h = idx&7;
  int e0 = rp[n], e1 = rp[n+1];
  float s = 0.f;
  for (int i=e0;i<e1;i++) s += ex[(size_t)eix[i]*8 + h];
  deninv[idx] = 1.f/(s + 1e-16f);
}

// ---------------- per-(edge,head) alpha = ex * deninv[dst] ----------------
__global__ void k_alpha(const int* __restrict__ ei, const float* __restrict__ ex,
                        const float* __restrict__ deninv, float* __restrict__ alpha, int E){
  int idx = blockIdx.x*256 + threadIdx.x;
  if (idx >= E*8) return;
  int e = idx>>3, h = idx&7;
  alpha[idx] = ex[idx] * deninv[ei[E+e]*8 + h];
}

// ---------------- fused layer-2 aggregation + route pooling (edge-centric) ----------------
// grid: (64 routes, 8 edge-chunks, 4 col-chunks); rs must be zeroed first
#define ECH 8
__global__ __launch_bounds__(256) void k_agg2pool(const int* __restrict__ ei,
    const int* __restrict__ rerp, const int* __restrict__ reix,
    const int* __restrict__ rrp,
    const float* __restrict__ alpha, const u16* __restrict__ CAT,
    const float* __restrict__ b3, float* __restrict__ rs){
  int r = blockIdx.x;
  int c = blockIdx.z*256 + threadIdx.x;   // 0..1023
  int h = c >> 7;
  int i0 = rerp[r], i1 = rerp[r+1];
  int per = (i1 - i0 + ECH - 1)/ECH;
  int s0 = i0 + blockIdx.y*per;
  int s1 = min(i1, s0 + per);
  float acc = 0.f;
  for (int i=s0;i<s1;i++){
    int e = reix[i];
    float a = alpha[(size_t)e*8 + h];
    acc += a * b2f(CAT[(size_t)ei[e]*2048 + c]);
  }
  if (blockIdx.y == 0) acc += (float)(rrp[r+1]-rrp[r]) * b3[c];
  atomicAdd(&rs[r*1024 + c], acc);
}

// ---------------- cumsum over routes -> ptop halves ----------------
__global__ void k_cumsum(const float* __restrict__ rs, float* __restrict__ ptop, int colbase){
  int c = blockIdx.x*256 + threadIdx.x; // 1024 cols
  float tot = 0.f;
  for (int r=0;r<64;r++) tot += rs[r*1024+c];
  float cs = 0.f;
  for (int r=0;r<64;r++){
    cs += rs[r*1024+c];
    ptop[r*4096 + colbase + c] = cs;
    ptop[r*4096 + colbase + 1024 + c] = tot - cs;
  }
}

// ---------------- BN over 64 routes (per column) ----------------
__global__ void k_pnbn(const float* __restrict__ ptop, const float* __restrict__ g, const float* __restrict__ b,
                       float* __restrict__ h){
  int c = blockIdx.x*256 + threadIdx.x; // 4096 cols
  float s=0.f, q=0.f;
  for (int r=0;r<64;r++){ float v = ptop[r*4096+c]; s+=v; q+=v*v; }
  float mu = s*(1.f/64.f), var = q*(1.f/64.f)-mu*mu;
  float rr = rsqrtf(var + 1e-5f);
  float gg = g[c], bb = b[c];
  for (int r=0;r<64;r++) h[r*4096+c] = (ptop[r*4096+c]-mu)*rr*gg + bb;
}

// ---------------- MLP split-K partials: PART[sk][64][Co] ----------------
#define KC 512
__global__ __launch_bounds__(256) void k_mlp_part(const float* __restrict__ In,
    const float* __restrict__ W, float* __restrict__ PART, int Ci, int Co){
  __shared__ float tin[64*64]; // 16 KiB: rows x ksub
  int c  = blockIdx.x*64 + (threadIdx.x&63);
  int rg = threadIdx.x>>6;     // 0..3
  int k0 = blockIdx.y*KC, k1 = min(Ci, k0+KC);
  float acc[16];
  #pragma unroll
  for (int j=0;j<16;j++) acc[j]=0.f;
  for (int ks=k0; ks<k1; ks+=64){
    int kw = min(64, k1-ks);
    __syncthreads();
    for (int i=threadIdx.x;i<64*64;i+=256){
      int r=i>>6, k=i&63;
      tin[i] = (k<kw)? In[(size_t)r*Ci + ks + k] : 0.f;
    }
    __syncthreads();
    if (c < Co){
      for (int k=0;k<kw;k+=4){
        float4 w4;
        w4.x = W[(size_t)(ks+k  )*Co + c];
        w4.y = W[(size_t)(ks+k+1)*Co + c];
        w4.z = W[(size_t)(ks+k+2)*Co + c];
        w4.w = W[(size_t)(ks+k+3)*Co + c];
        #pragma unroll
        for (int j=0;j<16;j++){
          float4 t4 = *(const float4*)(&tin[(rg*16+j)*64 + k]); // broadcast read
          acc[j] += t4.x*w4.x + t4.y*w4.y + t4.z*w4.z + t4.w*w4.w;
        }
      }
    }
  }
  if (c < Co){
    float* P = PART + (size_t)blockIdx.y*64*Co;
    #pragma unroll
    for (int j=0;j<16;j++)
      P[(size_t)(rg*16+j)*Co + c] = acc[j];
  }
}

// ---------------- MLP reduce: Out = act(sum_sk PART + bias) ----------------
__global__ void k_mlp_red(const float* __restrict__ PART, const float* __restrict__ bias,
                          float* __restrict__ Out, int Co, int SK, int act){
  int idx = blockIdx.x*256 + threadIdx.x;
  if (idx >= 64*Co) return;
  int c = idx % Co;
  float s = bias[c];
  for (int sk=0; sk<SK; sk++) s += PART[(size_t)sk*64*Co + idx];
  if (act) s = s>0.f ? s : 0.01f*s;
  Out[idx] = s;
}

// ---------------- sigmoid + output (f32) ----------------
__global__ void k_sigout(const float* __restrict__ h8, float* __restrict__ out){
  int r = threadIdx.x;
  if (r < 64){
    float p = 1.f/(1.f + __expf(-h8[r]));
    out[r] = p;
    out[64+r] = 0.f;
  }
}

extern "C" void kernel_launch(void* const* d_in, const int* in_sizes, int n_in,
                              void* d_out, int out_size, void* d_ws, size_t ws_size,
                              hipStream_t stream)
{
  const float* x_p1   = (const float*)d_in[0];
  const float* x_p2   = (const float*)d_in[1];
  const float* x_full = (const float*)d_in[2];
  const float* ea_p1  = (const float*)d_in[3];
  const float* ea_p2  = (const float*)d_in[4];
  const float* ea_full= (const float*)d_in[5];
  const int* ei_p1  = (const int*)d_in[6];
  const int* ei_p2  = (const int*)d_in[7];
  const int* ei_full= (const int*)d_in[8];
  const int* route_p1 = (const int*)d_in[9];
  const int* route_p2 = (const int*)d_in[10];
  const float *Wl1=(const float*)d_in[11], *Wr1=(const float*)d_in[12], *We1=(const float*)d_in[13], *att1=(const float*)d_in[14], *b1=(const float*)d_in[15];
  const float *Wl2=(const float*)d_in[16], *Wr2=(const float*)d_in[17], *We2=(const float*)d_in[18], *att2=(const float*)d_in[19], *b2=(const float*)d_in[20];
  const float *Wl3=(const float*)d_in[21], *Wr3=(const float*)d_in[22], *We3=(const float*)d_in[23], *att3=(const float*)d_in[24], *b3=(const float*)d_in[25];
  const float *bng=(const float*)d_in[26], *bnb=(const float*)d_in[27], *png=(const float*)d_in[28], *pnb=(const float*)d_in[29];
  const float *W[8], *Cb[8];
  for (int i=0;i<8;i++){ W[i]=(const float*)d_in[30+2*i]; Cb[i]=(const float*)d_in[31+2*i]; }

  char* w = (char*)d_ws;
  size_t off = 0;
  auto alloc = [&](size_t bytes)->char*{ char* p = w + off; off += (bytes + 255) & ~(size_t)255; return p; };
  u16* P1bf = (u16*)alloc((size_t)NN*512*2);
  u16* P2bf = (u16*)alloc((size_t)NN*512*2);
  u16* FGbf = (u16*)alloc((size_t)NN*512*2);
  char* BIG = alloc((size_t)NN*2048*2);           // phase1: XL|XR|EXf  phase3: CAT
  u16*   XLbf = (u16*)BIG;
  u16*   XRbf = (u16*)(BIG + (size_t)NN*512*2);
  float* EXf  = (float*)(BIG + (size_t)NN*1024*2);
  u16*   CATbf= (u16*)BIG;
  u16*   Bt   = (u16*)alloc((size_t)2048*1024*2);
  float* EX2 = (float*)alloc((size_t)EPAR*8*4);
  float* DEN = (float*)alloc((size_t)NN*8*4);
  float* ALPHA=(float*)alloc((size_t)EPAR*8*4);
  float* st1 = (float*)alloc(1024*4);
  float* st2 = (float*)alloc(1024*4);
  float* stF = (float*)alloc(1024*4);
  float* rs1 = (float*)alloc(64*1024*4);
  float* rs2 = (float*)alloc(64*1024*4);
  float* PTOP= (float*)alloc(64*4096*4);
  float* H0  = (float*)alloc(64*4096*4);
  float* H1  = (float*)alloc(64*4096*4);
  float* PART= (float*)alloc((size_t)8*64*2048*4);
  int* cnt = (int*)alloc(NN*4);
  int* wp  = (int*)alloc(NN*4);
  int* rpF = (int*)alloc((NN+1)*4);
  int* rp1 = (int*)alloc((NN+1)*4);
  int* rp2 = (int*)alloc((NN+1)*4);
  int* eixF= (int*)alloc((size_t)EFULL*4);
  int* eix1= (int*)alloc((size_t)EPAR*4);
  int* eix2= (int*)alloc((size_t)EPAR*4);
  int* rr1 = (int*)alloc(65*4);
  int* rr2 = (int*)alloc(65*4);
  int* rerp1=(int*)alloc(65*4);
  int* rerp2=(int*)alloc(65*4);
  int* nix1= (int*)alloc(NN*4);
  int* nix2= (int*)alloc(NN*4);
  int* reix1=(int*)alloc((size_t)EPAR*4);
  int* reix2=(int*)alloc((size_t)EPAR*4);
  if (ws_size < off){ k_fail<<<1,128,0,stream>>>((float*)d_out); return; }

  // ---- CSR builds (edges by dst) ----
  auto build_csr = [&](const int* dstp, int E, int* rp, int* eix){
    hipMemsetAsync(cnt, 0, NN*4, stream);
    k_count<<<(E+255)/256, 256, 0, stream>>>(dstp, cnt, E);
    k_scan <<<1, 1024, 0, stream>>>(cnt, rp, wp);
    k_fill <<<(E+255)/256, 256, 0, stream>>>(dstp, wp, eix, E);
  };
  build_csr(ei_full+EFULL, EFULL, rpF, eixF);
  build_csr(ei_p1+EPAR,   EPAR,  rp1, eix1);
  build_csr(ei_p2+EPAR,   EPAR,  rp2, eix2);

  // ---- route CSR (nodes by route) ----
  auto build_route = [&](const int* route, int* rrp, int* nix){
    hipMemsetAsync(cnt, 0, 64*4, stream);
    k_count <<<(NN+255)/256, 256, 0, stream>>>(route, cnt, NN);
    k_scan64<<<1, 64, 0, stream>>>(cnt, rrp, wp);
    k_fill  <<<(NN+255)/256, 256, 0, stream>>>(route, wp, nix, NN);
  };
  build_route(route_p1, rr1, nix1);
  build_route(route_p2, rr2, nix2);

  // ---- route-edge CSR (edges by route of dst) ----
  auto build_redge = [&](const int* dstp, const int* route, int* rerp, int* reix){
    hipMemsetAsync(cnt, 0, 64*4, stream);
    k_counte<<<(EPAR+255)/256, 256, 0, stream>>>(dstp, route, cnt, EPAR);
    k_scan64<<<1, 64, 0, stream>>>(cnt, rerp, wp);
    k_fille <<<(EPAR+255)/256, 256, 0, stream>>>(dstp, route, wp, reix, EPAR);
  };
  build_redge(ei_p1+EPAR, route_p1, rerp1, reix1);
  build_redge(ei_p2+EPAR, route_p2, rerp2, reix2);

  // ---- B pre-transpose for layer-2 GEMM ----
  k_bt<<<dim3(16,16,2), 256, 0, stream>>>(Wl3, Wr3, Bt);

  // ---- layer-1 GAT (three graphs, sequential, shared XL/XR/EX temps) ----
  auto gat1 = [&](const float* x, const int* ei, const float* ea, const int* rp, const int* eix,
                  const float* Wl, const float* Wr, const float* We, const float* att, const float* bias,
                  u16* out, int E){
    k_xw   <<<dim3(NN,2), 256, 0, stream>>>(x, Wl, Wr, XLbf, XRbf);
    k_edge1<<<(E+3)/4,  256, 0, stream>>>(ei, ea, We, att, XLbf, XRbf, EXf, E);
    k_agg1 <<<(NN+3)/4, 256, 0, stream>>>(ei, rp, eix, EXf, XLbf, bias, out, E);
  };
  gat1(x_full, ei_full, ea_full, rpF, eixF, Wl2, Wr2, We2, att2, b2, FGbf, EFULL);
  gat1(x_p1,   ei_p1,   ea_p1,   rp1, eix1, Wl1, Wr1, We1, att1, b1, P1bf, EPAR);
  gat1(x_p2,   ei_p2,   ea_p2,   rp2, eix2, Wl1, Wr1, We1, att1, b1, P2bf, EPAR);

  // ---- BatchNorm (batch stats) applied in place; FG half normalized once ----
  hipMemsetAsync(st1, 0, 1024*4, stream);
  hipMemsetAsync(st2, 0, 1024*4, stream);
  hipMemsetAsync(stF, 0, 1024*4, stream);
  k_bnstats<<<dim3(8,16), 256, 0, stream>>>(P1bf, st1);
  k_bnstats<<<dim3(8,16), 256, 0, stream>>>(P2bf, st2);
  k_bnstats<<<dim3(8,16), 256, 0, stream>>>(FGbf, stF);
  int nbn = (NN*512+255)/256;
  k_bnapply<<<nbn, 256, 0, stream>>>(P1bf, st1, bng, bnb, 0);
  k_bnapply<<<nbn, 256, 0, stream>>>(P2bf, st2, bng, bnb, 0);
  k_bnapply<<<nbn, 256, 0, stream>>>(FGbf, stF, bng, bnb, 512);

  // ---- layer-2 GAT + fused route pooling, per parent ----
  auto layer2 = [&](const u16* Pbf, const int* ei, const float* ea, const int* rp, const int* eix,
                    const int* rrp, const int* rerp, const int* reix, float* rs){
    k_gemm <<<dim3(16, (NN+127)/128), 256, 0, stream>>>(Pbf, FGbf, Bt, CATbf, NN);
    k_edge2<<<(EPAR+3)/4, 256, 0, stream>>>(ei, ea, We3, att3, CATbf, EX2, EPAR);
    k_den  <<<(NN*8+255)/256, 256, 0, stream>>>(rp, eix, EX2, DEN);
    k_alpha<<<(EPAR*8+255)/256, 256, 0, stream>>>(ei, EX2, DEN, ALPHA, EPAR);
    hipMemsetAsync(rs, 0, 64*1024*4, stream);
    k_agg2pool<<<dim3(64,ECH,4), 256, 0, stream>>>(ei, rerp, reix, rrp, ALPHA, CATbf, b3, rs);
  };
  layer2(P1bf, ei_p1, ea_p1, rp1, eix1, rr1, rerp1, reix1, rs1);
  layer2(P2bf, ei_p2, ea_p2, rp2, eix2, rr2, rerp2, reix2, rs2);

  // ---- cumsum/route features + pn BN ----
  k_cumsum<<<4, 256, 0, stream>>>(rs1, PTOP, 0);
  k_cumsum<<<4, 256, 0, stream>>>(rs2, PTOP, 2048);
  k_pnbn  <<<16, 256, 0, stream>>>(PTOP, png, pnb, H0);

  // ---- MLP (split-K partials + reduce) ----
  int dims[9] = {4096, 2048, 1024, 512, 256, 128, 64, 32, 1};
  float* bufs[2] = {H0, H1};
  for (int i=0;i<8;i++){
    int Ci = dims[i], Co = dims[i+1];
    int SK = (Ci + KC - 1)/KC;
    k_mlp_part<<<dim3((Co+63)/64, SK), 256, 0, stream>>>(bufs[i&1], W[i], PART, Ci, Co);
    k_mlp_red <<<(64*Co+255)/256, 256, 0, stream>>>(PART, Cb[i], bufs[(i+1)&1], Co, SK, (i<7)?1:0);
  }
  k_sigout<<<1, 64, 0, stream>>>(bufs[0], (float*)d_out);
}

// Round 7
// 2238.648 us; speedup vs baseline: 2.1067x; 1.1742x over previous
//
#include <hip/hip_runtime.h>
#include <stdint.h>

typedef unsigned short u16;
typedef unsigned int   u32;
typedef __attribute__((ext_vector_type(8))) short bf16x8;
typedef __attribute__((ext_vector_type(4))) float f32x4;

#define NN    30000
#define EFULL 240000
#define EPAR  30000

__device__ __forceinline__ float b2f(u16 u){ u32 x=((u32)u)<<16; float f; __builtin_memcpy(&f,&x,4); return f; }
__device__ __forceinline__ u16 f2b(float f){ u32 x; __builtin_memcpy(&x,&f,4); x += 0x7fffu + ((x>>16)&1u); return (u16)(x>>16); }

__device__ __forceinline__ void gload_lds16(const u16* g, u16* l){
  __builtin_amdgcn_global_load_lds((const __attribute__((address_space(1))) void*)g,
                                   (__attribute__((address_space(3))) void*)l, 16, 0, 0);
}

// ---------------- sentinel: workspace too small ----------------
__global__ void k_fail(float* out){ int t=threadIdx.x; if(t<128) out[t]=2.0f; }

// ---------------- CSR build ----------------
__global__ void k_count(const int* __restrict__ dstp, int* __restrict__ cnt, int E){
  int e = blockIdx.x*256 + threadIdx.x;
  if (e < E) atomicAdd(&cnt[dstp[e]], 1);
}

__global__ void k_scan(const int* __restrict__ cnt, int* __restrict__ rp, int* __restrict__ wp){
  __shared__ int sums[1024];
  int t = threadIdx.x;
  const int CH = (NN + 1023)/1024; // 30
  int c0 = t*CH;
  int s = 0;
  for (int i=0;i<CH;i++){ int idx=c0+i; s += (idx<NN)? cnt[idx] : 0; }
  sums[t] = s; __syncthreads();
  for (int off=1; off<1024; off<<=1){
    int v = (t>=off)? sums[t-off] : 0;
    __syncthreads();
    sums[t] += v;
    __syncthreads();
  }
  int run = (t==0)? 0 : sums[t-1];
  for (int i=0;i<CH;i++){
    int idx=c0+i;
    if (idx<NN){ rp[idx]=run; wp[idx]=run; run += cnt[idx]; }
  }
  if (t==1023) rp[NN] = sums[1023];
}

__global__ void k_scan64(const int* __restrict__ cnt, int* __restrict__ rp, int* __restrict__ wp){
  if (threadIdx.x==0){
    int run=0;
    for(int i=0;i<64;i++){ rp[i]=run; wp[i]=run; run+=cnt[i]; }
    rp[64]=run;
  }
}

__global__ void k_fill(const int* __restrict__ dstp, int* __restrict__ wp, int* __restrict__ eix, int E){
  int e = blockIdx.x*256 + threadIdx.x;
  if (e < E){ int p = atomicAdd(&wp[dstp[e]], 1); eix[p] = e; }
}

// route-of-dst edge CSR helpers
__global__ void k_counte(const int* __restrict__ dstp, const int* __restrict__ route,
                         int* __restrict__ cnt, int E){
  int e = blockIdx.x*256 + threadIdx.x;
  if (e < E) atomicAdd(&cnt[route[dstp[e]]], 1);
}
__global__ void k_fille(const int* __restrict__ dstp, const int* __restrict__ route,
                        int* __restrict__ wp, int* __restrict__ reix, int E){
  int e = blockIdx.x*256 + threadIdx.x;
  if (e < E){ int p = atomicAdd(&wp[route[dstp[e]]], 1); reix[p] = e; }
}

// ---------------- layer-1 x@W (F=16 -> 512), both L and R, bf16 out ----------------
__global__ __launch_bounds__(256) void k_xw(const float* __restrict__ x,
                                            const float* __restrict__ Wl, const float* __restrict__ Wr,
                                            u16* __restrict__ xl, u16* __restrict__ xr){
  int n = blockIdx.x;
  int c = blockIdx.y*256 + threadIdx.x;
  float xv[16];
  #pragma unroll
  for (int k=0;k<16;k++) xv[k] = x[n*16+k];
  float aL=0.f, aR=0.f;
  #pragma unroll
  for (int k=0;k<16;k++){
    aL += xv[k]*Wl[k*512+c];
    aR += xv[k]*Wr[k*512+c];
  }
  xl[(size_t)n*512+c]=f2b(aL); xr[(size_t)n*512+c]=f2b(aR);
}

// ---------------- fused layer-1 GAT: logits+softmax+aggregate, wave per node ----------------
__global__ __launch_bounds__(256) void k_gat1f(const int* __restrict__ ei,
    const float* __restrict__ ea,
    const int* __restrict__ rp, const int* __restrict__ eix,
    const float* __restrict__ We, const float* __restrict__ att,
    const u16* __restrict__ xl, const u16* __restrict__ xr,
    const float* __restrict__ bias, u16* __restrict__ out){
  int lane = threadIdx.x & 63;
  int n = blockIdx.x*4 + (threadIdx.x>>6);
  if (n >= NN) return;
  int j0 = lane*8;
  float we8[8], at8[8], rv8[8];
  bf16x8 rv = *(const bf16x8*)(xr + (size_t)n*512 + j0);
  #pragma unroll
  for (int j=0;j<8;j++){ we8[j]=We[j0+j]; at8[j]=att[j0+j]; rv8[j]=b2f((u16)rv[j]); }
  int r0 = rp[n], r1 = rp[n+1];
  float den = 0.f;
  for (int i=r0;i<r1;i++){
    int e = eix[i];
    int src = ei[e];
    float eaw = ea[e];
    bf16x8 lv = *(const bf16x8*)(xl + (size_t)src*512 + j0);
    float logit = 0.f;
    #pragma unroll
    for (int j=0;j<8;j++){
      float v = b2f((u16)lv[j]) + rv8[j] + eaw*we8[j];
      v = v>0.f? v : 0.2f*v;
      logit += v*at8[j];
    }
    logit += __shfl_xor(logit,1);
    logit += __shfl_xor(logit,2);
    logit += __shfl_xor(logit,4);
    den += __expf(logit);
  }
  float inv = 1.f/(den + 1e-16f);
  float acc[8] = {0,0,0,0,0,0,0,0};
  for (int i=r0;i<r1;i++){
    int e = eix[i];
    int src = ei[e];
    float eaw = ea[e];
    bf16x8 lv = *(const bf16x8*)(xl + (size_t)src*512 + j0);
    float lvf[8];
    float logit = 0.f;
    #pragma unroll
    for (int j=0;j<8;j++){
      lvf[j] = b2f((u16)lv[j]);
      float v = lvf[j] + rv8[j] + eaw*we8[j];
      v = v>0.f? v : 0.2f*v;
      logit += v*at8[j];
    }
    logit += __shfl_xor(logit,1);
    logit += __shfl_xor(logit,2);
    logit += __shfl_xor(logit,4);
    float a = __expf(logit)*inv;
    #pragma unroll
    for (int j=0;j<8;j++) acc[j] += a*lvf[j];
  }
  #pragma unroll
  for (int j=0;j<8;j++) out[(size_t)n*512 + j0 + j] = f2b(acc[j] + bias[j0+j]);
}

// ---------------- BN stats, coalesced row-band (thread = u32 col-pair) ----------------
__global__ __launch_bounds__(256) void k_bnstats(const u16* __restrict__ P, float* __restrict__ st){
  int t = threadIdx.x;
  const u32* Pu = (const u32*)P; // [NN][256] u32 pairs
  int r0 = blockIdx.x*250, r1 = r0+250;
  float s0=0.f,s1=0.f,q0=0.f,q1=0.f;
  for (int r=r0;r<r1;r++){
    u32 v = Pu[(size_t)r*256 + t];
    float a = b2f((u16)(v & 0xffffu));
    float b = b2f((u16)(v >> 16));
    s0+=a; q0+=a*a; s1+=b; q1+=b*b;
  }
  atomicAdd(&st[2*t],       s0);
  atomicAdd(&st[2*t+1],     s1);
  atomicAdd(&st[512+2*t],   q0);
  atomicAdd(&st[512+2*t+1], q1);
}

// ---------------- BN apply in-place (bf16), coff selects gamma/beta columns ----------------
__global__ __launch_bounds__(256) void k_bnapply(u16* __restrict__ P, const float* __restrict__ st,
    const float* __restrict__ g, const float* __restrict__ b, int coff){
  int idx = blockIdx.x*256 + threadIdx.x;
  if (idx >= NN*512) return;
  int c = idx & 511;
  const float invN = 1.f/30000.f;
  float mu = st[c]*invN;
  float var = st[512+c]*invN - mu*mu;
  float r = rsqrtf(var + 1e-5f);
  float v = b2f(P[idx]);
  P[idx] = f2b((v-mu)*r*g[coff+c] + b[coff+c]);
}

// ---------------- B pre-transpose + bf16: Bt[2048][1024] ----------------
__global__ __launch_bounds__(256) void k_bt(const float* __restrict__ B0, const float* __restrict__ B1,
                                            u16* __restrict__ Bt){
  __shared__ u16 tile[64][65];
  int bk = blockIdx.x;        // k tile
  int bn = blockIdx.y;        // n tile
  const float* B = blockIdx.z ? B1 : B0;
  int nb = blockIdx.z*1024;
  for (int i = threadIdx.x; i < 64*64; i += 256){
    int r = i>>6, c = i&63;
    tile[c][r] = f2b(B[(size_t)(bk*64+r)*1024 + bn*64 + c]);
  }
  __syncthreads();
  for (int i = threadIdx.x; i < 64*64; i += 256){
    int r = i>>6, c = i&63;
    Bt[(size_t)(nb + bn*64 + r)*1024 + bk*64 + c] = tile[r][c];
  }
}

// ---------------- MFMA GEMM: CAT[M,2048] = [A0|A1][M,1024] @ Bt^T, bf16 out ----------------
// XCD-swizzled block order + both-sides LDS XOR swizzle (linear gload_lds dest,
// pre-swizzled per-lane global source; reads XOR chunk with row&7).
__global__ __launch_bounds__(256) void k_gemm(const u16* __restrict__ A0, const u16* __restrict__ A1,
    const u16* __restrict__ Bt, u16* __restrict__ C, int M){
  __shared__ u16 As[128*64];
  __shared__ u16 Bs[128*64];
  // grid is (16, 235) = 3760 blocks = 8 XCDs x 470
  int lin = blockIdx.y*16 + blockIdx.x;
  int wg  = (lin&7)*470 + (lin>>3);
  int n0 = (wg & 15)*128;
  int m0 = (wg >> 4)*128;
  int t = threadIdx.x;
  int wave = t>>6, lane = t&63;
  int wm = (wave>>1)*64, wn = (wave&1)*64;
  int rr = lane&15, kq = (lane>>4)*8;
  int srow = t>>3;                       // 0..31
  int scol = (t&7)*8;                    // linear LDS dest chunk
  int ssw  = ((t&7) ^ (srow&7))*8;       // swizzled global source chunk
  f32x4 acc[4][4];
  #pragma unroll
  for (int m=0;m<4;m++)
    #pragma unroll
    for (int n=0;n<4;n++){ acc[m][n][0]=0.f; acc[m][n][1]=0.f; acc[m][n][2]=0.f; acc[m][n][3]=0.f; }
  for (int k0=0; k0<1024; k0+=64){
    const u16* Ap = (k0 < 512) ? A0 : A1;
    int kc = k0 & 511;
    #pragma unroll
    for (int i=0;i<4;i++){
      int row = i*32 + srow;
      gload_lds16(Ap + (size_t)(m0+row)*512 + kc + ssw, As + row*64 + scol);
    }
    #pragma unroll
    for (int i=0;i<4;i++){
      int row = i*32 + srow;
      gload_lds16(Bt + (size_t)(n0+row)*1024 + k0 + ssw, Bs + row*64 + scol);
    }
    __syncthreads();
    #pragma unroll
    for (int ks=0; ks<2; ks++){
      int pc = ((ks*4 + (lane>>4)) ^ (lane&7))*8;  // phys chunk for row&7 == lane&7
      bf16x8 af[4], bb[4];
      #pragma unroll
      for (int m=0;m<4;m++) af[m] = *(const bf16x8*)(&As[(wm + m*16 + rr)*64 + pc]);
      #pragma unroll
      for (int n=0;n<4;n++) bb[n] = *(const bf16x8*)(&Bs[(wn + n*16 + rr)*64 + pc]);
      #pragma unroll
      for (int m=0;m<4;m++)
        #pragma unroll
        for (int n=0;n<4;n++)
          acc[m][n] = __builtin_amdgcn_mfma_f32_16x16x32_bf16(af[m], bb[n], acc[m][n], 0, 0, 0);
    }
    __syncthreads();
  }
  int rq = (lane>>4)*4;
  #pragma unroll
  for (int m=0;m<4;m++)
    #pragma unroll
    for (int n=0;n<4;n++)
      #pragma unroll
      for (int j=0;j<4;j++){
        int row = m0 + wm + m*16 + rq + j;
        int col = n0 + wn + n*16 + rr;
        if (row < M) C[(size_t)row*2048 + col] = f2b(acc[m][n][j]);
      }
}

// ---------------- edge logits dim=1024 (layer 2, CAT bf16) ----------------
__global__ __launch_bounds__(256) void k_edge2(const int* __restrict__ ei, const float* __restrict__ ea,
    const float* __restrict__ We, const float* __restrict__ att,
    const u16* __restrict__ CAT, float* __restrict__ ex, int E){
  int lane = threadIdx.x & 63;
  int e = blockIdx.x*4 + (threadIdx.x>>6);
  if (e >= E) return;
  int src = ei[e], dst = ei[E+e];
  float eaw = ea[e];
  int j0 = lane*16;
  bf16x8 l0 = *(const bf16x8*)(CAT + (size_t)src*2048 + j0);
  bf16x8 l1 = *(const bf16x8*)(CAT + (size_t)src*2048 + j0 + 8);
  bf16x8 r0 = *(const bf16x8*)(CAT + (size_t)dst*2048 + 1024 + j0);
  bf16x8 r1 = *(const bf16x8*)(CAT + (size_t)dst*2048 + 1024 + j0 + 8);
  float logit = 0.f;
  #pragma unroll
  for (int j=0;j<16;j++){
    float lvj = b2f((u16)((j<8)? l0[j] : l1[j-8]));
    float rvj = b2f((u16)((j<8)? r0[j] : r1[j-8]));
    float v = lvj + rvj + eaw*We[j0+j];
    v = v > 0.f ? v : 0.2f*v;
    logit += v * att[j0+j];
  }
  logit += __shfl_xor(logit,1);
  logit += __shfl_xor(logit,2);
  logit += __shfl_xor(logit,4);
  if ((lane&7)==0) ex[(size_t)e*8 + (lane>>3)] = __expf(logit);
}

// ---------------- per-(node,head) inverse denominator ----------------
__global__ void k_den(const int* __restrict__ rp, const int* __restrict__ eix,
                      const float* __restrict__ ex, float* __restrict__ deninv){
  int idx = blockIdx.x*256 + threadIdx.x;
  if (idx >= NN*8) return;
  int n = idx>>3, h = idx&7;
  int e0 = rp[n], e1 = rp[n+1];
  float s = 0.f;
  for (int i=e0;i<e1;i++) s += ex[(size_t)eix[i]*8 + h];
  deninv[idx] = 1.f/(s + 1e-16f);
}

// ---------------- per-(edge,head) alpha = ex * deninv[dst] ----------------
__global__ void k_alpha(const int* __restrict__ ei, const float* __restrict__ ex,
                        const float* __restrict__ deninv, float* __restrict__ alpha, int E){
  int idx = blockIdx.x*256 + threadIdx.x;
  if (idx >= E*8) return;
  int e = idx>>3, h = idx&7;
  alpha[idx] = ex[idx] * deninv[ei[E+e]*8 + h];
}

// ---------------- fused layer-2 aggregation + route pooling (edge-centric) ----------------
#define ECH 8
__global__ __launch_bounds__(256) void k_agg2pool(const int* __restrict__ ei,
    const int* __restrict__ rerp, const int* __restrict__ reix,
    const int* __restrict__ rrp,
    const float* __restrict__ alpha, const u16* __restrict__ CAT,
    const float* __restrict__ b3, float* __restrict__ rs){
  int r = blockIdx.x;
  int c = blockIdx.z*256 + threadIdx.x;   // 0..1023
  int h = c >> 7;
  int i0 = rerp[r], i1 = rerp[r+1];
  int per = (i1 - i0 + ECH - 1)/ECH;
  int s0 = i0 + blockIdx.y*per;
  int s1 = min(i1, s0 + per);
  float acc = 0.f;
  for (int i=s0;i<s1;i++){
    int e = reix[i];
    float a = alpha[(size_t)e*8 + h];
    acc += a * b2f(CAT[(size_t)ei[e]*2048 + c]);
  }
  if (blockIdx.y == 0) acc += (float)(rrp[r+1]-rrp[r]) * b3[c];
  atomicAdd(&rs[r*1024 + c], acc);
}

// ---------------- cumsum over routes -> ptop halves ----------------
__global__ void k_cumsum(const float* __restrict__ rs, float* __restrict__ ptop, int colbase){
  int c = blockIdx.x*256 + threadIdx.x; // 1024 cols
  float tot = 0.f;
  for (int r=0;r<64;r++) tot += rs[r*1024+c];
  float cs = 0.f;
  for (int r=0;r<64;r++){
    cs += rs[r*1024+c];
    ptop[r*4096 + colbase + c] = cs;
    ptop[r*4096 + colbase + 1024 + c] = tot - cs;
  }
}

// ---------------- BN over 64 routes (per column) ----------------
__global__ void k_pnbn(const float* __restrict__ ptop, const float* __restrict__ g, const float* __restrict__ b,
                       float* __restrict__ h){
  int c = blockIdx.x*256 + threadIdx.x; // 4096 cols
  float s=0.f, q=0.f;
  for (int r=0;r<64;r++){ float v = ptop[r*4096+c]; s+=v; q+=v*v; }
  float mu = s*(1.f/64.f), var = q*(1.f/64.f)-mu*mu;
  float rr = rsqrtf(var + 1e-5f);
  float gg = g[c], bb = b[c];
  for (int r=0;r<64;r++) h[r*4096+c] = (ptop[r*4096+c]-mu)*rr*gg + bb;
}

// ---------------- MLP split-K partials: PART[sk][64][Co] ----------------
#define KC 512
__global__ __launch_bounds__(256) void k_mlp_part(const float* __restrict__ In,
    const float* __restrict__ W, float* __restrict__ PART, int Ci, int Co){
  __shared__ float tin[64*64]; // 16 KiB: rows x ksub
  int c  = blockIdx.x*64 + (threadIdx.x&63);
  int rg = threadIdx.x>>6;     // 0..3
  int k0 = blockIdx.y*KC, k1 = min(Ci, k0+KC);
  float acc[16];
  #pragma unroll
  for (int j=0;j<16;j++) acc[j]=0.f;
  for (int ks=k0; ks<k1; ks+=64){
    int kw = min(64, k1-ks);
    __syncthreads();
    for (int i=threadIdx.x;i<64*64;i+=256){
      int r=i>>6, k=i&63;
      tin[i] = (k<kw)? In[(size_t)r*Ci + ks + k] : 0.f;
    }
    __syncthreads();
    if (c < Co){
      for (int k=0;k<kw;k+=4){
        float4 w4;
        w4.x = W[(size_t)(ks+k  )*Co + c];
        w4.y = W[(size_t)(ks+k+1)*Co + c];
        w4.z = W[(size_t)(ks+k+2)*Co + c];
        w4.w = W[(size_t)(ks+k+3)*Co + c];
        #pragma unroll
        for (int j=0;j<16;j++){
          float4 t4 = *(const float4*)(&tin[(rg*16+j)*64 + k]); // broadcast read
          acc[j] += t4.x*w4.x + t4.y*w4.y + t4.z*w4.z + t4.w*w4.w;
        }
      }
    }
  }
  if (c < Co){
    float* P = PART + (size_t)blockIdx.y*64*Co;
    #pragma unroll
    for (int j=0;j<16;j++)
      P[(size_t)(rg*16+j)*Co + c] = acc[j];
  }
}

// ---------------- MLP reduce: Out = act(sum_sk PART + bias) ----------------
__global__ void k_mlp_red(const float* __restrict__ PART, const float* __restrict__ bias,
                          float* __restrict__ Out, int Co, int SK, int act){
  int idx = blockIdx.x*256 + threadIdx.x;
  if (idx >= 64*Co) return;
  int c = idx % Co;
  float s = bias[c];
  for (int sk=0; sk<SK; sk++) s += PART[(size_t)sk*64*Co + idx];
  if (act) s = s>0.f ? s : 0.01f*s;
  Out[idx] = s;
}

// ---------------- sigmoid + output (f32) ----------------
__global__ void k_sigout(const float* __restrict__ h8, float* __restrict__ out){
  int r = threadIdx.x;
  if (r < 64){
    float p = 1.f/(1.f + __expf(-h8[r]));
    out[r] = p;
    out[64+r] = 0.f;
  }
}

extern "C" void kernel_launch(void* const* d_in, const int* in_sizes, int n_in,
                              void* d_out, int out_size, void* d_ws, size_t ws_size,
                              hipStream_t stream)
{
  const float* x_p1   = (const float*)d_in[0];
  const float* x_p2   = (const float*)d_in[1];
  const float* x_full = (const float*)d_in[2];
  const float* ea_p1  = (const float*)d_in[3];
  const float* ea_p2  = (const float*)d_in[4];
  const float* ea_full= (const float*)d_in[5];
  const int* ei_p1  = (const int*)d_in[6];
  const int* ei_p2  = (const int*)d_in[7];
  const int* ei_full= (const int*)d_in[8];
  const int* route_p1 = (const int*)d_in[9];
  const int* route_p2 = (const int*)d_in[10];
  const float *Wl1=(const float*)d_in[11], *Wr1=(const float*)d_in[12], *We1=(const float*)d_in[13], *att1=(const float*)d_in[14], *b1=(const float*)d_in[15];
  const float *Wl2=(const float*)d_in[16], *Wr2=(const float*)d_in[17], *We2=(const float*)d_in[18], *att2=(const float*)d_in[19], *b2=(const float*)d_in[20];
  const float *Wl3=(const float*)d_in[21], *Wr3=(const float*)d_in[22], *We3=(const float*)d_in[23], *att3=(const float*)d_in[24], *b3=(const float*)d_in[25];
  const float *bng=(const float*)d_in[26], *bnb=(const float*)d_in[27], *png=(const float*)d_in[28], *pnb=(const float*)d_in[29];
  const float *W[8], *Cb[8];
  for (int i=0;i<8;i++){ W[i]=(const float*)d_in[30+2*i]; Cb[i]=(const float*)d_in[31+2*i]; }

  char* w = (char*)d_ws;
  size_t off = 0;
  auto alloc = [&](size_t bytes)->char*{ char* p = w + off; off += (bytes + 255) & ~(size_t)255; return p; };
  u16* P1bf = (u16*)alloc((size_t)NN*512*2);
  u16* P2bf = (u16*)alloc((size_t)NN*512*2);
  u16* FGbf = (u16*)alloc((size_t)NN*512*2);
  char* BIG = alloc((size_t)NN*2048*2);           // phase1: XL|XR  phase3: CAT
  u16*   XLbf = (u16*)BIG;
  u16*   XRbf = (u16*)(BIG + (size_t)NN*512*2);
  u16*   CATbf= (u16*)BIG;
  u16*   Bt   = (u16*)alloc((size_t)2048*1024*2);
  float* EX2 = (float*)alloc((size_t)EPAR*8*4);
  float* DEN = (float*)alloc((size_t)NN*8*4);
  float* ALPHA=(float*)alloc((size_t)EPAR*8*4);
  float* st1 = (float*)alloc(1024*4);
  float* st2 = (float*)alloc(1024*4);
  float* stF = (float*)alloc(1024*4);
  float* rs1 = (float*)alloc(64*1024*4);
  float* rs2 = (float*)alloc(64*1024*4);
  float* PTOP= (float*)alloc(64*4096*4);
  float* H0  = (float*)alloc(64*4096*4);
  float* H1  = (float*)alloc(64*4096*4);
  float* PART= (float*)alloc((size_t)8*64*2048*4);
  int* cnt = (int*)alloc(NN*4);
  int* wp  = (int*)alloc(NN*4);
  int* rpF = (int*)alloc((NN+1)*4);
  int* rp1 = (int*)alloc((NN+1)*4);
  int* rp2 = (int*)alloc((NN+1)*4);
  int* eixF= (int*)alloc((size_t)EFULL*4);
  int* eix1= (int*)alloc((size_t)EPAR*4);
  int* eix2= (int*)alloc((size_t)EPAR*4);
  int* rr1 = (int*)alloc(65*4);
  int* rr2 = (int*)alloc(65*4);
  int* rerp1=(int*)alloc(65*4);
  int* rerp2=(int*)alloc(65*4);
  int* nix1= (int*)alloc(NN*4);
  int* nix2= (int*)alloc(NN*4);
  int* reix1=(int*)alloc((size_t)EPAR*4);
  int* reix2=(int*)alloc((size_t)EPAR*4);
  if (ws_size < off){ k_fail<<<1,128,0,stream>>>((float*)d_out); return; }

  // ---- CSR builds (edges by dst) ----
  auto build_csr = [&](const int* dstp, int E, int* rp, int* eix){
    hipMemsetAsync(cnt, 0, NN*4, stream);
    k_count<<<(E+255)/256, 256, 0, stream>>>(dstp, cnt, E);
    k_scan <<<1, 1024, 0, stream>>>(cnt, rp, wp);
    k_fill <<<(E+255)/256, 256, 0, stream>>>(dstp, wp, eix, E);
  };
  build_csr(ei_full+EFULL, EFULL, rpF, eixF);
  build_csr(ei_p1+EPAR,   EPAR,  rp1, eix1);
  build_csr(ei_p2+EPAR,   EPAR,  rp2, eix2);

  // ---- route CSR (nodes by route) ----
  auto build_route = [&](const int* route, int* rrp, int* nix){
    hipMemsetAsync(cnt, 0, 64*4, stream);
    k_count <<<(NN+255)/256, 256, 0, stream>>>(route, cnt, NN);
    k_scan64<<<1, 64, 0, stream>>>(cnt, rrp, wp);
    k_fill  <<<(NN+255)/256, 256, 0, stream>>>(route, wp, nix, NN);
  };
  build_route(route_p1, rr1, nix1);
  build_route(route_p2, rr2, nix2);

  // ---- route-edge CSR (edges by route of dst) ----
  auto build_redge = [&](const int* dstp, const int* route, int* rerp, int* reix){
    hipMemsetAsync(cnt, 0, 64*4, stream);
    k_counte<<<(EPAR+255)/256, 256, 0, stream>>>(dstp, route, cnt, EPAR);
    k_scan64<<<1, 64, 0, stream>>>(cnt, rerp, wp);
    k_fille <<<(EPAR+255)/256, 256, 0, stream>>>(dstp, route, wp, reix, EPAR);
  };
  build_redge(ei_p1+EPAR, route_p1, rerp1, reix1);
  build_redge(ei_p2+EPAR, route_p2, rerp2, reix2);

  // ---- B pre-transpose for layer-2 GEMM ----
  k_bt<<<dim3(16,16,2), 256, 0, stream>>>(Wl3, Wr3, Bt);

  // ---- layer-1 GAT (fused edge+softmax+aggregate) ----
  auto gat1 = [&](const float* x, const int* ei, const float* ea, const int* rp, const int* eix,
                  const float* Wl, const float* Wr, const float* We, const float* att, const float* bias,
                  u16* out){
    k_xw   <<<dim3(NN,2), 256, 0, stream>>>(x, Wl, Wr, XLbf, XRbf);
    k_gat1f<<<(NN+3)/4, 256, 0, stream>>>(ei, ea, rp, eix, We, att, XLbf, XRbf, bias, out);
  };
  gat1(x_full, ei_full, ea_full, rpF, eixF, Wl2, Wr2, We2, att2, b2, FGbf);
  gat1(x_p1,   ei_p1,   ea_p1,   rp1, eix1, Wl1, Wr1, We1, att1, b1, P1bf);
  gat1(x_p2,   ei_p2,   ea_p2,   rp2, eix2, Wl1, Wr1, We1, att1, b1, P2bf);

  // ---- BatchNorm (batch stats) applied in place; FG half normalized once ----
  hipMemsetAsync(st1, 0, 1024*4, stream);
  hipMemsetAsync(st2, 0, 1024*4, stream);
  hipMemsetAsync(stF, 0, 1024*4, stream);
  k_bnstats<<<120, 256, 0, stream>>>(P1bf, st1);
  k_bnstats<<<120, 256, 0, stream>>>(P2bf, st2);
  k_bnstats<<<120, 256, 0, stream>>>(FGbf, stF);
  int nbn = (NN*512+255)/256;
  k_bnapply<<<nbn, 256, 0, stream>>>(P1bf, st1, bng, bnb, 0);
  k_bnapply<<<nbn, 256, 0, stream>>>(P2bf, st2, bng, bnb, 0);
  k_bnapply<<<nbn, 256, 0, stream>>>(FGbf, stF, bng, bnb, 512);

  // ---- layer-2 GAT + fused route pooling, per parent ----
  auto layer2 = [&](const u16* Pbf, const int* ei, const float* ea, const int* rp, const int* eix,
                    const int* rrp, const int* rerp, const int* reix, float* rs){
    k_gemm <<<dim3(16, (NN+127)/128), 256, 0, stream>>>(Pbf, FGbf, Bt, CATbf, NN);
    k_edge2<<<(EPAR+3)/4, 256, 0, stream>>>(ei, ea, We3, att3, CATbf, EX2, EPAR);
    k_den  <<<(NN*8+255)/256, 256, 0, stream>>>(rp, eix, EX2, DEN);
    k_alpha<<<(EPAR*8+255)/256, 256, 0, stream>>>(ei, EX2, DEN, ALPHA, EPAR);
    hipMemsetAsync(rs, 0, 64*1024*4, stream);
    k_agg2pool<<<dim3(64,ECH,4), 256, 0, stream>>>(ei, rerp, reix, rrp, ALPHA, CATbf, b3, rs);
  };
  layer2(P1bf, ei_p1, ea_p1, rp1, eix1, rr1, rerp1, reix1, rs1);
  layer2(P2bf, ei_p2, ea_p2, rp2, eix2, rr2, rerp2, reix2, rs2);

  // ---- cumsum/route features + pn BN ----
  k_cumsum<<<4, 256, 0, stream>>>(rs1, PTOP, 0);
  k_cumsum<<<4, 256, 0, stream>>>(rs2, PTOP, 2048);
  k_pnbn  <<<16, 256, 0, stream>>>(PTOP, png, pnb, H0);

  // ---- MLP (split-K partials + reduce) ----
  int dims[9] = {4096, 2048, 1024, 512, 256, 128, 64, 32, 1};
  float* bufs[2] = {H0, H1};
  for (int i=0;i<8;i++){
    int Ci = dims[i], Co = dims[i+1];
    int SK = (Ci + KC - 1)/KC;
    k_mlp_part<<<dim3((Co+63)/64, SK), 256, 0, stream>>>(bufs[i&1], W[i], PART, Ci, Co);
    k_mlp_red <<<(64*Co+255)/256, 256, 0, stream>>>(PART, Cb[i], bufs[(i+1)&1], Co, SK, (i<7)?1:0);
  }
  k_sigout<<<1, 64, 0, stream>>>(bufs[0], (float*)d_out);
}

// Round 8
// 1701.114 us; speedup vs baseline: 2.7725x; 1.3160x over previous
//
#include <hip/hip_runtime.h>
#include <stdint.h>

typedef unsigned short u16;
typedef unsigned int   u32;
typedef __attribute__((ext_vector_type(8))) short bf16x8;
typedef __attribute__((ext_vector_type(4))) float f32x4;

#define NN    30000
#define EFULL 240000
#define EPAR  30000

__device__ __forceinline__ float b2f(u16 u){ u32 x=((u32)u)<<16; float f; __builtin_memcpy(&f,&x,4); return f; }
__device__ __forceinline__ u16 f2b(float f){ u32 x; __builtin_memcpy(&x,&f,4); x += 0x7fffu + ((x>>16)&1u); return (u16)(x>>16); }

__device__ __forceinline__ void gload_lds16(const u16* g, u16* l){
  __builtin_amdgcn_global_load_lds((const __attribute__((address_space(1))) void*)g,
                                   (__attribute__((address_space(3))) void*)l, 16, 0, 0);
}

// ---------------- sentinel: workspace too small ----------------
__global__ void k_fail(float* out){ int t=threadIdx.x; if(t<128) out[t]=2.0f; }

// ---------------- batched edge-CSR build (z = graph: 0 full, 1 p1, 2 p2) ----------------
__global__ void k_counte3(const int* __restrict__ d0, const int* __restrict__ d1, const int* __restrict__ d2,
                          int* __restrict__ c0, int* __restrict__ c1, int* __restrict__ c2){
  int z = blockIdx.z;
  const int* d = z==0? d0 : z==1? d1 : d2;
  int* c = z==0? c0 : z==1? c1 : c2;
  int E = z==0? EFULL : EPAR;
  int e = blockIdx.x*256 + threadIdx.x;
  if (e < E) atomicAdd(&c[d[e]], 1);
}

__global__ void k_scan3(const int* __restrict__ c0, const int* __restrict__ c1, const int* __restrict__ c2,
                        int* __restrict__ r0, int* __restrict__ r1, int* __restrict__ r2,
                        int* __restrict__ w0, int* __restrict__ w1, int* __restrict__ w2){
  __shared__ int sums[1024];
  int z = blockIdx.x;
  const int* cnt = z==0? c0 : z==1? c1 : c2;
  int* rp = z==0? r0 : z==1? r1 : r2;
  int* wp = z==0? w0 : z==1? w1 : w2;
  int t = threadIdx.x;
  const int CH = (NN + 1023)/1024; // 30
  int c00 = t*CH;
  int s = 0;
  for (int i=0;i<CH;i++){ int idx=c00+i; s += (idx<NN)? cnt[idx] : 0; }
  sums[t] = s; __syncthreads();
  for (int off=1; off<1024; off<<=1){
    int v = (t>=off)? sums[t-off] : 0;
    __syncthreads();
    sums[t] += v;
    __syncthreads();
  }
  int run = (t==0)? 0 : sums[t-1];
  for (int i=0;i<CH;i++){
    int idx=c00+i;
    if (idx<NN){ rp[idx]=run; wp[idx]=run; run += cnt[idx]; }
  }
  if (t==1023) rp[NN] = sums[1023];
}

__global__ void k_fill3(const int* __restrict__ d0, const int* __restrict__ d1, const int* __restrict__ d2,
                        int* __restrict__ w0, int* __restrict__ w1, int* __restrict__ w2,
                        int* __restrict__ x0, int* __restrict__ x1, int* __restrict__ x2){
  int z = blockIdx.z;
  const int* d = z==0? d0 : z==1? d1 : d2;
  int* w = z==0? w0 : z==1? w1 : w2;
  int* x = z==0? x0 : z==1? x1 : x2;
  int E = z==0? EFULL : EPAR;
  int e = blockIdx.x*256 + threadIdx.x;
  if (e < E){ int p = atomicAdd(&w[d[e]], 1); x[p] = e; }
}

// ---------------- batched 64-bin builds (z: 0/1 route nodes, 2/3 route-of-dst edges) ----------------
__global__ void k_count64(const int* __restrict__ rt0, const int* __restrict__ rt1,
                          const int* __restrict__ d0, const int* __restrict__ d1,
                          int* __restrict__ c0, int* __restrict__ c1,
                          int* __restrict__ c2, int* __restrict__ c3){
  int z = blockIdx.z;
  int i = blockIdx.x*256 + threadIdx.x;
  if (i >= NN) return;  // NN == EPAR
  if      (z==0) atomicAdd(&c0[rt0[i]], 1);
  else if (z==1) atomicAdd(&c1[rt1[i]], 1);
  else if (z==2) atomicAdd(&c2[rt0[d0[i]]], 1);
  else           atomicAdd(&c3[rt1[d1[i]]], 1);
}

__global__ void k_scan64x4(const int* __restrict__ c0, const int* __restrict__ c1,
                           const int* __restrict__ c2, const int* __restrict__ c3,
                           int* __restrict__ r0, int* __restrict__ r1,
                           int* __restrict__ r2, int* __restrict__ r3,
                           int* __restrict__ w0, int* __restrict__ w1,
                           int* __restrict__ w2, int* __restrict__ w3){
  int t = threadIdx.x;
  if (t >= 4) return;
  const int* c = t==0?c0:t==1?c1:t==2?c2:c3;
  int* r = t==0?r0:t==1?r1:t==2?r2:r3;
  int* w = t==0?w0:t==1?w1:t==2?w2:w3;
  int run=0;
  for (int i=0;i<64;i++){ r[i]=run; w[i]=run; run+=c[i]; }
  r[64]=run;
}

__global__ void k_fill64(const int* __restrict__ rt0, const int* __restrict__ rt1,
                         const int* __restrict__ d0, const int* __restrict__ d1,
                         int* __restrict__ w0, int* __restrict__ w1,
                         int* __restrict__ w2, int* __restrict__ w3,
                         int* __restrict__ x0, int* __restrict__ x1,
                         int* __restrict__ x2, int* __restrict__ x3){
  int z = blockIdx.z;
  int i = blockIdx.x*256 + threadIdx.x;
  if (i >= NN) return;
  if      (z==0){ int p=atomicAdd(&w0[rt0[i]],1);      x0[p]=i; }
  else if (z==1){ int p=atomicAdd(&w1[rt1[i]],1);      x1[p]=i; }
  else if (z==2){ int p=atomicAdd(&w2[rt0[d0[i]]],1);  x2[p]=i; }
  else          { int p=atomicAdd(&w3[rt1[d1[i]]],1);  x3[p]=i; }
}

// ---------------- layer-1 x@W (F=16 -> 512), both L and R, bf16 out ----------------
__global__ __launch_bounds__(256) void k_xw(const float* __restrict__ x,
                                            const float* __restrict__ Wl, const float* __restrict__ Wr,
                                            u16* __restrict__ xl, u16* __restrict__ xr){
  int n = blockIdx.x;
  int c = blockIdx.y*256 + threadIdx.x;
  float xv[16];
  #pragma unroll
  for (int k=0;k<16;k++) xv[k] = x[n*16+k];
  float aL=0.f, aR=0.f;
  #pragma unroll
  for (int k=0;k<16;k++){
    aL += xv[k]*Wl[k*512+c];
    aR += xv[k]*Wr[k*512+c];
  }
  xl[(size_t)n*512+c]=f2b(aL); xr[(size_t)n*512+c]=f2b(aR);
}

// ---------------- fused layer-1 GAT: single-pass logits+softmax+aggregate ----------------
__global__ __launch_bounds__(256) void k_gat1f(const int* __restrict__ ei,
    const float* __restrict__ ea,
    const int* __restrict__ rp, const int* __restrict__ eix,
    const float* __restrict__ We, const float* __restrict__ att,
    const u16* __restrict__ xl, const u16* __restrict__ xr,
    const float* __restrict__ bias, u16* __restrict__ out){
  int lane = threadIdx.x & 63;
  int n = blockIdx.x*4 + (threadIdx.x>>6);
  if (n >= NN) return;
  int j0 = lane*8;
  float we8[8], at8[8], rv8[8];
  bf16x8 rv = *(const bf16x8*)(xr + (size_t)n*512 + j0);
  #pragma unroll
  for (int j=0;j<8;j++){ we8[j]=We[j0+j]; at8[j]=att[j0+j]; rv8[j]=b2f((u16)rv[j]); }
  int r0 = rp[n], r1 = rp[n+1];
  float den = 0.f;
  float acc[8] = {0,0,0,0,0,0,0,0};
  for (int i=r0;i<r1;i++){
    int e = eix[i];
    int src = ei[e];
    float eaw = ea[e];
    bf16x8 lv = *(const bf16x8*)(xl + (size_t)src*512 + j0);
    float lvf[8];
    float logit = 0.f;
    #pragma unroll
    for (int j=0;j<8;j++){
      lvf[j] = b2f((u16)lv[j]);
      float v = lvf[j] + rv8[j] + eaw*we8[j];
      v = v>0.f? v : 0.2f*v;
      logit += v*at8[j];
    }
    logit += __shfl_xor(logit,1);
    logit += __shfl_xor(logit,2);
    logit += __shfl_xor(logit,4);
    float a = __expf(logit);
    den += a;
    #pragma unroll
    for (int j=0;j<8;j++) acc[j] += a*lvf[j];
  }
  float inv = 1.f/(den + 1e-16f);
  #pragma unroll
  for (int j=0;j<8;j++) out[(size_t)n*512 + j0 + j] = f2b(acc[j]*inv + bias[j0+j]);
}

// ---------------- BN stats, batched z=3, coalesced row-band ----------------
__global__ __launch_bounds__(256) void k_bnstats(const u16* __restrict__ P1, const u16* __restrict__ P2,
    const u16* __restrict__ PF, float* __restrict__ s1, float* __restrict__ s2, float* __restrict__ sF){
  int z = blockIdx.y;
  const u16* P = z==0? P1 : z==1? P2 : PF;
  float* st = z==0? s1 : z==1? s2 : sF;
  int t = threadIdx.x;
  const u32* Pu = (const u32*)P;
  int r0 = blockIdx.x*250, r1 = r0+250;
  float a0=0.f,a1=0.f,q0=0.f,q1=0.f;
  for (int r=r0;r<r1;r++){
    u32 v = Pu[(size_t)r*256 + t];
    float a = b2f((u16)(v & 0xffffu));
    float b = b2f((u16)(v >> 16));
    a0+=a; q0+=a*a; a1+=b; q1+=b*b;
  }
  atomicAdd(&st[2*t],       a0);
  atomicAdd(&st[2*t+1],     a1);
  atomicAdd(&st[512+2*t],   q0);
  atomicAdd(&st[512+2*t+1], q1);
}

// ---------------- BN apply in-place (bf16), batched z=3 ----------------
__global__ __launch_bounds__(256) void k_bnapply(u16* __restrict__ P1, u16* __restrict__ P2, u16* __restrict__ PF,
    const float* __restrict__ s1, const float* __restrict__ s2, const float* __restrict__ sF,
    const float* __restrict__ g, const float* __restrict__ b){
  int z = blockIdx.y;
  u16* P = z==0? P1 : z==1? P2 : PF;
  const float* st = z==0? s1 : z==1? s2 : sF;
  int coff = (z==2)? 512 : 0;
  int idx = blockIdx.x*256 + threadIdx.x;
  if (idx >= NN*512) return;
  int c = idx & 511;
  const float invN = 1.f/30000.f;
  float mu = st[c]*invN;
  float var = st[512+c]*invN - mu*mu;
  float r = rsqrtf(var + 1e-5f);
  float v = b2f(P[idx]);
  P[idx] = f2b((v-mu)*r*g[coff+c] + b[coff+c]);
}

// ---------------- B pre-transpose + bf16: Bt[2048][1024] ----------------
__global__ __launch_bounds__(256) void k_bt(const float* __restrict__ B0, const float* __restrict__ B1,
                                            u16* __restrict__ Bt){
  __shared__ u16 tile[64][65];
  int bk = blockIdx.x;
  int bn = blockIdx.y;
  const float* B = blockIdx.z ? B1 : B0;
  int nb = blockIdx.z*1024;
  for (int i = threadIdx.x; i < 64*64; i += 256){
    int r = i>>6, c = i&63;
    tile[c][r] = f2b(B[(size_t)(bk*64+r)*1024 + bn*64 + c]);
  }
  __syncthreads();
  for (int i = threadIdx.x; i < 64*64; i += 256){
    int r = i>>6, c = i&63;
    Bt[(size_t)(nb + bn*64 + r)*1024 + bk*64 + c] = tile[r][c];
  }
}

// ---------------- MFMA GEMM: CAT[M,2048] = [A0|A1][M,1024] @ Bt^T, bf16 out ----------------
__global__ __launch_bounds__(256) void k_gemm(const u16* __restrict__ A0, const u16* __restrict__ A1,
    const u16* __restrict__ Bt, u16* __restrict__ C, int M){
  __shared__ u16 As[128*64];
  __shared__ u16 Bs[128*64];
  int lin = blockIdx.y*16 + blockIdx.x;
  int wg  = (lin&7)*470 + (lin>>3);
  int n0 = (wg & 15)*128;
  int m0 = (wg >> 4)*128;
  int t = threadIdx.x;
  int wave = t>>6, lane = t&63;
  int wm = (wave>>1)*64, wn = (wave&1)*64;
  int rr = lane&15, kq = (lane>>4)*8;
  int srow = t>>3;
  int scol = (t&7)*8;
  int ssw  = ((t&7) ^ (srow&7))*8;
  f32x4 acc[4][4];
  #pragma unroll
  for (int m=0;m<4;m++)
    #pragma unroll
    for (int n=0;n<4;n++){ acc[m][n][0]=0.f; acc[m][n][1]=0.f; acc[m][n][2]=0.f; acc[m][n][3]=0.f; }
  for (int k0=0; k0<1024; k0+=64){
    const u16* Ap = (k0 < 512) ? A0 : A1;
    int kc = k0 & 511;
    #pragma unroll
    for (int i=0;i<4;i++){
      int row = i*32 + srow;
      gload_lds16(Ap + (size_t)(m0+row)*512 + kc + ssw, As + row*64 + scol);
    }
    #pragma unroll
    for (int i=0;i<4;i++){
      int row = i*32 + srow;
      gload_lds16(Bt + (size_t)(n0+row)*1024 + k0 + ssw, Bs + row*64 + scol);
    }
    __syncthreads();
    #pragma unroll
    for (int ks=0; ks<2; ks++){
      int pc = ((ks*4 + (lane>>4)) ^ (lane&7))*8;
      bf16x8 af[4], bb[4];
      #pragma unroll
      for (int m=0;m<4;m++) af[m] = *(const bf16x8*)(&As[(wm + m*16 + rr)*64 + pc]);
      #pragma unroll
      for (int n=0;n<4;n++) bb[n] = *(const bf16x8*)(&Bs[(wn + n*16 + rr)*64 + pc]);
      #pragma unroll
      for (int m=0;m<4;m++)
        #pragma unroll
        for (int n=0;n<4;n++)
          acc[m][n] = __builtin_amdgcn_mfma_f32_16x16x32_bf16(af[m], bb[n], acc[m][n], 0, 0, 0);
    }
    __syncthreads();
  }
  int rq = (lane>>4)*4;
  #pragma unroll
  for (int m=0;m<4;m++)
    #pragma unroll
    for (int n=0;n<4;n++)
      #pragma unroll
      for (int j=0;j<4;j++){
        int row = m0 + wm + m*16 + rq + j;
        int col = n0 + wn + n*16 + rr;
        if (row < M) C[(size_t)row*2048 + col] = f2b(acc[m][n][j]);
      }
}

// ---------------- edge logits dim=1024 (layer 2, CAT bf16) ----------------
__global__ __launch_bounds__(256) void k_edge2(const int* __restrict__ ei, const float* __restrict__ ea,
    const float* __restrict__ We, const float* __restrict__ att,
    const u16* __restrict__ CAT, float* __restrict__ ex, int E){
  int lane = threadIdx.x & 63;
  int e = blockIdx.x*4 + (threadIdx.x>>6);
  if (e >= E) return;
  int src = ei[e], dst = ei[E+e];
  float eaw = ea[e];
  int j0 = lane*16;
  bf16x8 l0 = *(const bf16x8*)(CAT + (size_t)src*2048 + j0);
  bf16x8 l1 = *(const bf16x8*)(CAT + (size_t)src*2048 + j0 + 8);
  bf16x8 r0 = *(const bf16x8*)(CAT + (size_t)dst*2048 + 1024 + j0);
  bf16x8 r1 = *(const bf16x8*)(CAT + (size_t)dst*2048 + 1024 + j0 + 8);
  float logit = 0.f;
  #pragma unroll
  for (int j=0;j<16;j++){
    float lvj = b2f((u16)((j<8)? l0[j] : l1[j-8]));
    float rvj = b2f((u16)((j<8)? r0[j] : r1[j-8]));
    float v = lvj + rvj + eaw*We[j0+j];
    v = v > 0.f ? v : 0.2f*v;
    logit += v * att[j0+j];
  }
  logit += __shfl_xor(logit,1);
  logit += __shfl_xor(logit,2);
  logit += __shfl_xor(logit,4);
  if ((lane&7)==0) ex[(size_t)e*8 + (lane>>3)] = __expf(logit);
}

// ---------------- fused per-(node,head) denominator + per-edge alpha ----------------
__global__ void k_denalpha(const int* __restrict__ rp, const int* __restrict__ eix,
                           const float* __restrict__ ex, float* __restrict__ alpha){
  int idx = blockIdx.x*256 + threadIdx.x;
  if (idx >= NN*8) return;
  int n = idx>>3, h = idx&7;
  int e0 = rp[n], e1 = rp[n+1];
  float s = 0.f;
  for (int i=e0;i<e1;i++) s += ex[(size_t)eix[i]*8 + h];
  float inv = 1.f/(s + 1e-16f);
  for (int i=e0;i<e1;i++){
    int e = eix[i];
    alpha[(size_t)e*8 + h] = ex[(size_t)e*8 + h]*inv;
  }
}

// ---------------- fused layer-2 aggregation + route pooling (edge-centric) ----------------
#define ECH 32
__global__ __launch_bounds__(256) void k_agg2pool(const int* __restrict__ ei,
    const int* __restrict__ rerp, const int* __restrict__ reix,
    const int* __restrict__ rrp,
    const float* __restrict__ alpha, const u16* __restrict__ CAT,
    const float* __restrict__ b3, float* __restrict__ rs){
  int r = blockIdx.x;
  int c = blockIdx.z*256 + threadIdx.x;   // 0..1023
  int h = c >> 7;
  int i0 = rerp[r], i1 = rerp[r+1];
  int per = (i1 - i0 + ECH - 1)/ECH;
  int s0 = i0 + blockIdx.y*per;
  int s1 = min(i1, s0 + per);
  float acc = 0.f;
  for (int i=s0;i<s1;i++){
    int e = reix[i];
    float a = alpha[(size_t)e*8 + h];
    acc += a * b2f(CAT[(size_t)ei[e]*2048 + c]);
  }
  if (blockIdx.y == 0) acc += (float)(rrp[r+1]-rrp[r]) * b3[c];
  if (s0 < s1 || blockIdx.y == 0) atomicAdd(&rs[r*1024 + c], acc);
}

// ---------------- cumsum over routes -> ptop halves (z = parent) ----------------
__global__ void k_cumsum(const float* __restrict__ rs1, const float* __restrict__ rs2,
                         float* __restrict__ ptop){
  const float* rs = blockIdx.y ? rs2 : rs1;
  int colbase = blockIdx.y ? 2048 : 0;
  int c = blockIdx.x*256 + threadIdx.x; // 1024 cols
  float tot = 0.f;
  for (int r=0;r<64;r++) tot += rs[r*1024+c];
  float cs = 0.f;
  for (int r=0;r<64;r++){
    cs += rs[r*1024+c];
    ptop[r*4096 + colbase + c] = cs;
    ptop[r*4096 + colbase + 1024 + c] = tot - cs;
  }
}

// ---------------- BN over 64 routes (per column) ----------------
__global__ void k_pnbn(const float* __restrict__ ptop, const float* __restrict__ g, const float* __restrict__ b,
                       float* __restrict__ h){
  int c = blockIdx.x*256 + threadIdx.x; // 4096 cols
  float s=0.f, q=0.f;
  for (int r=0;r<64;r++){ float v = ptop[r*4096+c]; s+=v; q+=v*v; }
  float mu = s*(1.f/64.f), var = q*(1.f/64.f)-mu*mu;
  float rr = rsqrtf(var + 1e-5f);
  float gg = g[c], bb = b[c];
  for (int r=0;r<64;r++) h[r*4096+c] = (ptop[r*4096+c]-mu)*rr*gg + bb;
}

// ---------------- MLP split-K partials: PART[sk][64][Co] ----------------
#define KC 512
__global__ __launch_bounds__(256) void k_mlp_part(const float* __restrict__ In,
    const float* __restrict__ W, float* __restrict__ PART, int Ci, int Co){
  __shared__ float tin[64*64];
  int c  = blockIdx.x*64 + (threadIdx.x&63);
  int rg = threadIdx.x>>6;
  int k0 = blockIdx.y*KC, k1 = min(Ci, k0+KC);
  float acc[16];
  #pragma unroll
  for (int j=0;j<16;j++) acc[j]=0.f;
  for (int ks=k0; ks<k1; ks+=64){
    int kw = min(64, k1-ks);
    __syncthreads();
    for (int i=threadIdx.x;i<64*64;i+=256){
      int r=i>>6, k=i&63;
      tin[i] = (k<kw)? In[(size_t)r*Ci + ks + k] : 0.f;
    }
    __syncthreads();
    if (c < Co){
      for (int k=0;k<kw;k+=4){
        float4 w4;
        w4.x = W[(size_t)(ks+k  )*Co + c];
        w4.y = W[(size_t)(ks+k+1)*Co + c];
        w4.z = W[(size_t)(ks+k+2)*Co + c];
        w4.w = W[(size_t)(ks+k+3)*Co + c];
        #pragma unroll
        for (int j=0;j<16;j++){
          float4 t4 = *(const float4*)(&tin[(rg*16+j)*64 + k]);
          acc[j] += t4.x*w4.x + t4.y*w4.y + t4.z*w4.z + t4.w*w4.w;
        }
      }
    }
  }
  if (c < Co){
    float* P = PART + (size_t)blockIdx.y*64*Co;
    #pragma unroll
    for (int j=0;j<16;j++)
      P[(size_t)(rg*16+j)*Co + c] = acc[j];
  }
}

// ---------------- MLP reduce: Out = act(sum_sk PART + bias) ----------------
__global__ void k_mlp_red(const float* __restrict__ PART, const float* __restrict__ bias,
                          float* __restrict__ Out, int Co, int SK, int act){
  int idx = blockIdx.x*256 + threadIdx.x;
  if (idx >= 64*Co) return;
  int c = idx % Co;
  float s = bias[c];
  for (int sk=0; sk<SK; sk++) s += PART[(size_t)sk*64*Co + idx];
  if (act) s = s>0.f ? s : 0.01f*s;
  Out[idx] = s;
}

// ---------------- fused MLP tail: 128 -> 64 -> 32 -> 1 + sigmoid ----------------
__global__ __launch_bounds__(256) void k_mlp_tail(const float* __restrict__ In,
    const float* __restrict__ W6, const float* __restrict__ c6,
    const float* __restrict__ W7, const float* __restrict__ c7,
    const float* __restrict__ W8, const float* __restrict__ c8,
    float* __restrict__ out){
  __shared__ float A[64*128];
  __shared__ float B[64*64];
  int t = threadIdx.x;
  for (int i=t;i<64*128;i+=256) A[i] = In[i];
  __syncthreads();
  // L6: 128 -> 64
  for (int idx=t; idx<64*64; idx+=256){
    int r=idx>>6, c=idx&63;
    float s=c6[c];
    for (int k=0;k<128;k++) s += A[r*128+k]*W6[k*64+c];
    B[idx] = s>0.f? s : 0.01f*s;
  }
  __syncthreads();
  // L7: 64 -> 32 (into A)
  for (int idx=t; idx<64*32; idx+=256){
    int r=idx>>5, c=idx&31;
    float s=c7[c];
    for (int k=0;k<64;k++) s += B[r*64+k]*W7[k*32+c];
    A[idx] = s>0.f? s : 0.01f*s;
  }
  __syncthreads();
  // L8 + sigmoid
  if (t<64){
    float s=c8[0];
    for (int k=0;k<32;k++) s += A[t*32+k]*W8[k];
    out[t] = 1.f/(1.f + __expf(-s));
    out[64+t] = 0.f;
  }
}

extern "C" void kernel_launch(void* const* d_in, const int* in_sizes, int n_in,
                              void* d_out, int out_size, void* d_ws, size_t ws_size,
                              hipStream_t stream)
{
  const float* x_p1   = (const float*)d_in[0];
  const float* x_p2   = (const float*)d_in[1];
  const float* x_full = (const float*)d_in[2];
  const float* ea_p1  = (const float*)d_in[3];
  const float* ea_p2  = (const float*)d_in[4];
  const float* ea_full= (const float*)d_in[5];
  const int* ei_p1  = (const int*)d_in[6];
  const int* ei_p2  = (const int*)d_in[7];
  const int* ei_full= (const int*)d_in[8];
  const int* route_p1 = (const int*)d_in[9];
  const int* route_p2 = (const int*)d_in[10];
  const float *Wl1=(const float*)d_in[11], *Wr1=(const float*)d_in[12], *We1=(const float*)d_in[13], *att1=(const float*)d_in[14], *b1=(const float*)d_in[15];
  const float *Wl2=(const float*)d_in[16], *Wr2=(const float*)d_in[17], *We2=(const float*)d_in[18], *att2=(const float*)d_in[19], *b2=(const float*)d_in[20];
  const float *Wl3=(const float*)d_in[21], *Wr3=(const float*)d_in[22], *We3=(const float*)d_in[23], *att3=(const float*)d_in[24], *b3=(const float*)d_in[25];
  const float *bng=(const float*)d_in[26], *bnb=(const float*)d_in[27], *png=(const float*)d_in[28], *pnb=(const float*)d_in[29];
  const float *W[8], *Cb[8];
  for (int i=0;i<8;i++){ W[i]=(const float*)d_in[30+2*i]; Cb[i]=(const float*)d_in[31+2*i]; }

  char* w = (char*)d_ws;
  size_t off = 0;
  auto alloc = [&](size_t bytes)->char*{ char* p = w + off; off += (bytes + 255) & ~(size_t)255; return p; };
  u16* P1bf = (u16*)alloc((size_t)NN*512*2);
  u16* P2bf = (u16*)alloc((size_t)NN*512*2);
  u16* FGbf = (u16*)alloc((size_t)NN*512*2);
  char* BIG = alloc((size_t)NN*2048*2);           // phase1: XL|XR  phase3: CAT
  u16*   XLbf = (u16*)BIG;
  u16*   XRbf = (u16*)(BIG + (size_t)NN*512*2);
  u16*   CATbf= (u16*)BIG;
  u16*   Bt   = (u16*)alloc((size_t)2048*1024*2);
  float* EX2 = (float*)alloc((size_t)EPAR*8*4);
  float* ALPHA=(float*)alloc((size_t)EPAR*8*4);
  float* st1 = (float*)alloc(1024*4);
  float* st2 = (float*)alloc(1024*4);
  float* stF = (float*)alloc(1024*4);
  float* rs1 = (float*)alloc(64*1024*4);
  float* rs2 = (float*)alloc(64*1024*4);
  float* PTOP= (float*)alloc(64*4096*4);
  float* H0  = (float*)alloc(64*4096*4);
  float* H1  = (float*)alloc(64*4096*4);
  float* PART= (float*)alloc((size_t)8*64*2048*4);
  // counter block (zeroed with ONE memset): cntF,cntA,cntB then 4x cnt64
  char* cnt_base = alloc(0);
  int* cntF = (int*)alloc(NN*4);
  int* cntA = (int*)alloc(NN*4);
  int* cntB = (int*)alloc(NN*4);
  int* c64a = (int*)alloc(64*4);
  int* c64b = (int*)alloc(64*4);
  int* c64c = (int*)alloc(64*4);
  int* c64d = (int*)alloc(64*4);
  size_t cnt_bytes = (size_t)((char*)alloc(0) - cnt_base);
  int* wpF = (int*)alloc(NN*4);
  int* wpA = (int*)alloc(NN*4);
  int* wpB = (int*)alloc(NN*4);
  int* w64a= (int*)alloc(64*4);
  int* w64b= (int*)alloc(64*4);
  int* w64c= (int*)alloc(64*4);
  int* w64d= (int*)alloc(64*4);
  int* rpF = (int*)alloc((NN+1)*4);
  int* rp1 = (int*)alloc((NN+1)*4);
  int* rp2 = (int*)alloc((NN+1)*4);
  int* eixF= (int*)alloc((size_t)EFULL*4);
  int* eix1= (int*)alloc((size_t)EPAR*4);
  int* eix2= (int*)alloc((size_t)EPAR*4);
  int* rr1 = (int*)alloc(65*4);
  int* rr2 = (int*)alloc(65*4);
  int* rerp1=(int*)alloc(65*4);
  int* rerp2=(int*)alloc(65*4);
  int* nix1= (int*)alloc(NN*4);
  int* nix2= (int*)alloc(NN*4);
  int* reix1=(int*)alloc((size_t)EPAR*4);
  int* reix2=(int*)alloc((size_t)EPAR*4);
  if (ws_size < off){ k_fail<<<1,128,0,stream>>>((float*)d_out); return; }

  // ---- zero all counters + stats + rs in 2 memsets ----
  hipMemsetAsync(cnt_base, 0, cnt_bytes, stream);
  hipMemsetAsync(st1, 0, 3*4096 + 2*64*1024*4 + 2*256, stream); // st1,st2,stF,rs1,rs2 (contiguous allocs)

  // ---- batched CSR builds ----
  k_counte3<<<dim3((EFULL+255)/256,1,3), 256, 0, stream>>>(ei_full+EFULL, ei_p1+EPAR, ei_p2+EPAR,
                                                           cntF, cntA, cntB);
  k_scan3  <<<3, 1024, 0, stream>>>(cntF, cntA, cntB, rpF, rp1, rp2, wpF, wpA, wpB);
  k_fill3  <<<dim3((EFULL+255)/256,1,3), 256, 0, stream>>>(ei_full+EFULL, ei_p1+EPAR, ei_p2+EPAR,
                                                           wpF, wpA, wpB, eixF, eix1, eix2);
  k_count64<<<dim3((NN+255)/256,1,4), 256, 0, stream>>>(route_p1, route_p2, ei_p1+EPAR, ei_p2+EPAR,
                                                        c64a, c64b, c64c, c64d);
  k_scan64x4<<<1, 64, 0, stream>>>(c64a,c64b,c64c,c64d, rr1,rr2,rerp1,rerp2, w64a,w64b,w64c,w64d);
  k_fill64 <<<dim3((NN+255)/256,1,4), 256, 0, stream>>>(route_p1, route_p2, ei_p1+EPAR, ei_p2+EPAR,
                                                        w64a,w64b,w64c,w64d, nix1,nix2,reix1,reix2);

  // ---- B pre-transpose for layer-2 GEMM ----
  k_bt<<<dim3(16,16,2), 256, 0, stream>>>(Wl3, Wr3, Bt);

  // ---- layer-1 GAT (single-pass fused) ----
  auto gat1 = [&](const float* x, const int* ei, const float* ea, const int* rp, const int* eix,
                  const float* Wl, const float* Wr, const float* We, const float* att, const float* bias,
                  u16* out){
    k_xw   <<<dim3(NN,2), 256, 0, stream>>>(x, Wl, Wr, XLbf, XRbf);
    k_gat1f<<<(NN+3)/4, 256, 0, stream>>>(ei, ea, rp, eix, We, att, XLbf, XRbf, bias, out);
  };
  gat1(x_full, ei_full, ea_full, rpF, eixF, Wl2, Wr2, We2, att2, b2, FGbf);
  gat1(x_p1,   ei_p1,   ea_p1,   rp1, eix1, Wl1, Wr1, We1, att1, b1, P1bf);
  gat1(x_p2,   ei_p2,   ea_p2,   rp2, eix2, Wl1, Wr1, We1, att1, b1, P2bf);

  // ---- BatchNorm batched ----
  k_bnstats<<<dim3(120,3), 256, 0, stream>>>(P1bf, P2bf, FGbf, st1, st2, stF);
  int nbn = (NN*512+255)/256;
  k_bnapply<<<dim3(nbn,3), 256, 0, stream>>>(P1bf, P2bf, FGbf, st1, st2, stF, bng, bnb);

  // ---- layer-2 GAT + fused route pooling, per parent ----
  auto layer2 = [&](const u16* Pbf, const int* ei, const float* ea, const int* rp, const int* eix,
                    const int* rrp, const int* rerp, const int* reix, float* rs){
    k_gemm <<<dim3(16, (NN+127)/128), 256, 0, stream>>>(Pbf, FGbf, Bt, CATbf, NN);
    k_edge2<<<(EPAR+3)/4, 256, 0, stream>>>(ei, ea, We3, att3, CATbf, EX2, EPAR);
    k_denalpha<<<(NN*8+255)/256, 256, 0, stream>>>(rp, eix, EX2, ALPHA);
    k_agg2pool<<<dim3(64,ECH,4), 256, 0, stream>>>(ei, rerp, reix, rrp, ALPHA, CATbf, b3, rs);
  };
  layer2(P1bf, ei_p1, ea_p1, rp1, eix1, rr1, rerp1, reix1, rs1);
  layer2(P2bf, ei_p2, ea_p2, rp2, eix2, rr2, rerp2, reix2, rs2);

  // ---- cumsum/route features + pn BN ----
  k_cumsum<<<dim3(4,2), 256, 0, stream>>>(rs1, rs2, PTOP);
  k_pnbn  <<<16, 256, 0, stream>>>(PTOP, png, pnb, H0);

  // ---- MLP: layers 1-5 split-K, tail fused ----
  int dims[9] = {4096, 2048, 1024, 512, 256, 128, 64, 32, 1};
  float* bufs[2] = {H0, H1};
  for (int i=0;i<5;i++){
    int Ci = dims[i], Co = dims[i+1];
    int SK = (Ci + KC - 1)/KC;
    k_mlp_part<<<dim3((Co+63)/64, SK), 256, 0, stream>>>(bufs[i&1], W[i], PART, Ci, Co);
    k_mlp_red <<<(64*Co+255)/256, 256, 0, stream>>>(PART, Cb[i], bufs[(i+1)&1], Co, SK, 1);
  }
  k_mlp_tail<<<1, 256, 0, stream>>>(bufs[1], W[5], Cb[5], W[6], Cb[6], W[7], Cb[7], (float*)d_out);
}